// Round 7
// baseline (866.195 us; speedup 1.0000x reference)
//
#include <hip/hip_runtime.h>

static constexpr int NN = 50000;
static constexpr int NE = 1000000;

typedef short bf16x8 __attribute__((ext_vector_type(8)));
typedef float f32x4 __attribute__((ext_vector_type(4)));

__device__ inline float bf2f_raw(unsigned short u) {
    return __uint_as_float(((unsigned int)u) << 16);
}
__device__ inline unsigned short f2bf(float f) {
    unsigned int u = __float_as_uint(f);
    u += 0x7fffu + ((u >> 16) & 1u);
    return (unsigned short)(u >> 16);
}
__device__ inline void fmax2(float& a0, float& a1, unsigned int v) {
    a0 = fmaxf(a0, bf2f_raw((unsigned short)(v & 0xffffu)));
    a1 = fmaxf(a1, bf2f_raw((unsigned short)(v >> 16)));
}
__device__ inline unsigned int pack2(float f0, float f1) {
    return (unsigned int)f2bf(f0) | ((unsigned int)f2bf(f1) << 16);
}
__device__ inline unsigned int addrelu2(unsigned int a, float t0, float t1) {
    float f0 = fmaxf(bf2f_raw((unsigned short)(a & 0xffffu)) + t0, 0.f);
    float f1 = fmaxf(bf2f_raw((unsigned short)(a >> 16)) + t1, 0.f);
    return pack2(f0, f1);
}

// ---------------- out init: out = x + b5 ----------------

__global__ void init_out_kernel(const float* __restrict__ x, const float* __restrict__ b5,
                                float* __restrict__ out) {
    int t = blockIdx.x * blockDim.x + threadIdx.x;
    if (t < NN * 3) out[t] = x[t] + b5[t % 3];
}

// ---------------- CSR build ----------------

__global__ void hist_kernel(const int* __restrict__ dst, int* __restrict__ deg) {
    int e = blockIdx.x * blockDim.x + threadIdx.x;
    if (e < NE) atomicAdd(&deg[dst[e]], 1);
}

// single-block scan, register-resident: one global read pass + one write pass
__global__ __launch_bounds__(1024) void scan_kernel(const int* __restrict__ deg,
                                                    int* __restrict__ rowstart,
                                                    int* __restrict__ cursor) {
    __shared__ int wave_sums[16];
    constexpr int CH = (NN + 1023) / 1024;  // 49
    int tid = threadIdx.x;
    int lane = tid & 63;
    int wave = tid >> 6;
    for (int i = tid; i < NN; i += 1024) cursor[i] = 0;  // replaces a memset dispatch
    int base = tid * CH;
    int vals[CH];
    int sum = 0;
    #pragma unroll
    for (int i = 0; i < CH; ++i) {
        int idx = base + i;
        vals[i] = (idx < NN) ? deg[idx] : 0;
        sum += vals[i];
    }
    // block-wide exclusive scan of per-thread sums
    int x = sum;
    #pragma unroll
    for (int off = 1; off < 64; off <<= 1) {
        int y = __shfl_up(x, off);
        if (lane >= off) x += y;
    }
    if (lane == 63) wave_sums[wave] = x;
    __syncthreads();
    if (wave == 0 && lane < 16) {
        int s = wave_sums[lane];
        #pragma unroll
        for (int off = 1; off < 16; off <<= 1) {
            int y = __shfl_up(s, off);
            if (lane >= off) s += y;
        }
        wave_sums[lane] = s;
    }
    __syncthreads();
    int run = (wave ? wave_sums[wave - 1] : 0) + x - sum;  // exclusive prefix
    #pragma unroll
    for (int i = 0; i < CH; ++i) {
        int idx = base + i;
        if (idx < NN) rowstart[idx] = run;
        run += vals[i];
    }
    if (tid == 1023) rowstart[NN] = run;
}

__global__ void scatter_kernel(const int* __restrict__ src, const int* __restrict__ dst,
                               const int* __restrict__ rowstart, int* __restrict__ cursor,
                               int* __restrict__ csr) {
    int e = blockIdx.x * blockDim.x + threadIdx.x;
    if (e < NE) {
        int d = dst[e];
        int pos = atomicAdd(&cursor[d], 1);
        csr[rowstart[d] + pos] = src[e];
    }
}

// ---------------- all weight prep in one dispatch ----------------

__global__ void prep_all_kernel(const float* __restrict__ W2, const float* __restrict__ W3,
                                const float* __restrict__ W4,
                                unsigned short* __restrict__ Bt2,
                                unsigned short* __restrict__ Bt3,
                                unsigned short* __restrict__ W4t) {
    int t = blockIdx.x * blockDim.x + threadIdx.x;
    if (t < 8192) {  // 64*128
        int k = t / 128, c = t % 128;
        float wt = W2[k * 128 + c];
        float wb = W2[(64 + k) * 128 + c];
        Bt2[c * 64 + k] = f2bf(wt - wb);
        Bt2[(128 + c) * 64 + k] = f2bf(wb);
    } else if (t < 8192 + 65536) {  // 128*512
        int u = t - 8192;
        int k = u / 512, c = u % 512;
        float wt = W3[k * 512 + c];
        float wb = W3[(128 + k) * 512 + c];
        Bt3[c * 128 + k] = f2bf(wt - wb);
        Bt3[(512 + c) * 128 + k] = f2bf(wb);
    } else if (t < 8192 + 65536 + 131072) {  // 512*256
        int u = t - 8192 - 65536;
        int k = u / 256, n = u % 256;
        W4t[n * 512 + k] = f2bf(W4[k * 256 + n]);
    }
}

// ---------------- conv1: as1[i] = [a1(64) | s1(64)] from x (K=3) ----------------
// a = x @ (Wtop - Wbot) + b1 ; s = x @ Wbot.  W1 is [6][64] row-major.

__global__ void conv1_as_kernel(const float* __restrict__ x, const float* __restrict__ W1,
                                const float* __restrict__ b1,
                                unsigned short* __restrict__ as1) {
    int t = blockIdx.x * blockDim.x + threadIdx.x;
    int i = t >> 7, c = t & 127;
    if (i >= NN) return;
    float x0 = x[i * 3 + 0], x1 = x[i * 3 + 1], x2 = x[i * 3 + 2];
    float v;
    if (c < 64) {
        v = x0 * (W1[c] - W1[192 + c]) + x1 * (W1[64 + c] - W1[256 + c]) +
            x2 * (W1[128 + c] - W1[320 + c]) + b1[c];
    } else {
        int cs = c - 64;
        v = x0 * W1[192 + cs] + x1 * W1[256 + cs] + x2 * W1[320 + cs];
    }
    as1[t] = f2bf(v);
}

// ---------------- channel-sliced fused edge-max + epilogue ----------------
// as rows are [a(C) | s(C)], row stride 2C. NS slices of 32 channels each.
// One wave handles one (node, slice): 16 edge-groups x 4 lanes, uint4 (8ch) per lane.
// Slice->XCD affinity via blockIdx%8 round-robin so each XCD's L2 holds one
// 3.2 MB slice working set (NS=16 uses gridDim.y=2 as two temporal phases).

template<int C, int NS>
__global__ __launch_bounds__(256) void edge_sliced_kernel(
    const unsigned short* __restrict__ as, const int* __restrict__ rowstart,
    const int* __restrict__ csr, unsigned short* __restrict__ xout) {
    constexpr int R = 2 * C;
    int bx = blockIdx.x;
    int slice, ng;
    if constexpr (NS == 16) {
        slice = ((bx & 7) << 1) + blockIdx.y;
        ng = bx >> 3;
    } else {
        slice = bx % NS;
        ng = bx / NS;
    }
    int node = ng * 4 + (threadIdx.x >> 6);
    int lane = threadIdx.x & 63;
    int g = lane >> 2, sub = lane & 3;
    if (node >= NN) return;
    int e0 = __builtin_amdgcn_readfirstlane(rowstart[node]);
    int e1 = __builtin_amdgcn_readfirstlane(rowstart[node + 1]);
    float acc[8];
    #pragma unroll
    for (int v = 0; v < 8; ++v) acc[v] = -INFINITY;
    const unsigned short* sb = as + C + slice * 32 + sub * 8;
    int nedge = e1 - e0;
    for (int base = 0; base < nedge; base += 64) {
        int rem = nedge - base;
        int myj = csr[(lane < rem) ? (e0 + base + lane) : e0];
        int cnt = rem < 64 ? rem : 64;
        int cp = (cnt + 31) & ~31;
        for (int q = 0; q < cp; q += 32) {
            int j0 = __shfl(myj, q + g);
            int j1 = __shfl(myj, q + 16 + g);
            uint4 v0 = *(const uint4*)(sb + (size_t)j0 * R);
            uint4 v1 = *(const uint4*)(sb + (size_t)j1 * R);
            fmax2(acc[0], acc[1], v0.x); fmax2(acc[2], acc[3], v0.y);
            fmax2(acc[4], acc[5], v0.z); fmax2(acc[6], acc[7], v0.w);
            fmax2(acc[0], acc[1], v1.x); fmax2(acc[2], acc[3], v1.y);
            fmax2(acc[4], acc[5], v1.z); fmax2(acc[6], acc[7], v1.w);
        }
    }
    #pragma unroll
    for (int m = 4; m <= 32; m <<= 1) {
        #pragma unroll
        for (int v = 0; v < 8; ++v) acc[v] = fmaxf(acc[v], __shfl_xor(acc[v], m));
    }
    if (g == 0) {
        uint4 av = *(const uint4*)(as + (size_t)node * R + slice * 32 + sub * 8);
        uint4 o;
        o.x = addrelu2(av.x, acc[0], acc[1]);
        o.y = addrelu2(av.y, acc[2], acc[3]);
        o.z = addrelu2(av.z, acc[4], acc[5]);
        o.w = addrelu2(av.w, acc[6], acc[7]);
        *(uint4*)(xout + (size_t)node * C + slice * 32 + sub * 8) = o;
    }
}

// ---------------- MFMA GEMM: C_bf16 = A_bf16[M,K] @ B (+bias on cols < bias_n) ----------------

__global__ __launch_bounds__(256) void mfma_gemm_kernel(
    const unsigned short* __restrict__ A, const unsigned short* __restrict__ Bt,
    const float* __restrict__ bias, int bias_n,
    unsigned short* __restrict__ C, int M, int N, int K) {
    __shared__ __align__(16) unsigned short Asl[128 * 40];
    __shared__ __align__(16) unsigned short Bsl[128 * 40];
    int tid = threadIdx.x;
    int mbase = blockIdx.y * 128, nbase = blockIdx.x * 128;
    int wave = tid >> 6, lane = tid & 63;
    int wm = (wave >> 1) * 64, wn = (wave & 1) * 64;
    int quad = lane >> 4, l16 = lane & 15;
    f32x4 acc[4][4] = {};
    for (int kb = 0; kb < K; kb += 32) {
        #pragma unroll
        for (int h = 0; h < 2; ++h) {
            int c = tid + h * 256;
            int r = c >> 2, kk = (c & 3) * 8;
            uint4 va = make_uint4(0u, 0u, 0u, 0u);
            int gr = mbase + r;
            if (gr < M) va = *(const uint4*)&A[(size_t)gr * K + kb + kk];
            *(uint4*)&Asl[r * 40 + kk] = va;
            uint4 vb = *(const uint4*)&Bt[(size_t)(nbase + r) * K + kb + kk];
            *(uint4*)&Bsl[r * 40 + kk] = vb;
        }
        __syncthreads();
        bf16x8 af[4], bfr[4];
        #pragma unroll
        for (int tt = 0; tt < 4; ++tt) {
            af[tt]  = *(const bf16x8*)&Asl[(wm + tt * 16 + l16) * 40 + quad * 8];
            bfr[tt] = *(const bf16x8*)&Bsl[(wn + tt * 16 + l16) * 40 + quad * 8];
        }
        #pragma unroll
        for (int mt = 0; mt < 4; ++mt)
            #pragma unroll
            for (int nt = 0; nt < 4; ++nt)
                acc[mt][nt] = __builtin_amdgcn_mfma_f32_16x16x32_bf16(
                    af[mt], bfr[nt], acc[mt][nt], 0, 0, 0);
        __syncthreads();
    }
    #pragma unroll
    for (int mt = 0; mt < 4; ++mt) {
        #pragma unroll
        for (int r = 0; r < 4; ++r) {
            int row = mbase + wm + mt * 16 + quad * 4 + r;
            if (row >= M) continue;
            #pragma unroll
            for (int nt = 0; nt < 4; ++nt) {
                int col = nbase + wn + nt * 16 + l16;
                float v = acc[mt][nt][r];
                if (col < bias_n) v += bias[col];
                C[(size_t)row * N + col] = f2bf(v);
            }
        }
    }
}

// ---------------- fused last stage: out += relu(x3@W4 + b4) @ W5 ----------------

__global__ __launch_bounds__(256) void mfma_gemm_w5_kernel(
    const unsigned short* __restrict__ A, const unsigned short* __restrict__ Bt,
    const float* __restrict__ b4, const float* __restrict__ W5,
    float* __restrict__ out, int M, int K) {
    __shared__ __align__(16) unsigned short Asl[128 * 40];
    __shared__ __align__(16) unsigned short Bsl[128 * 40];
    int tid = threadIdx.x;
    int mbase = blockIdx.y * 128, nbase = blockIdx.x * 128;
    int wave = tid >> 6, lane = tid & 63;
    int wm = (wave >> 1) * 64, wn = (wave & 1) * 64;
    int quad = lane >> 4, l16 = lane & 15;
    f32x4 acc[4][4] = {};
    for (int kb = 0; kb < K; kb += 32) {
        #pragma unroll
        for (int h = 0; h < 2; ++h) {
            int c = tid + h * 256;
            int r = c >> 2, kk = (c & 3) * 8;
            uint4 va = make_uint4(0u, 0u, 0u, 0u);
            int gr = mbase + r;
            if (gr < M) va = *(const uint4*)&A[(size_t)gr * K + kb + kk];
            *(uint4*)&Asl[r * 40 + kk] = va;
            uint4 vb = *(const uint4*)&Bt[(size_t)(nbase + r) * K + kb + kk];
            *(uint4*)&Bsl[r * 40 + kk] = vb;
        }
        __syncthreads();
        bf16x8 af[4], bfr[4];
        #pragma unroll
        for (int tt = 0; tt < 4; ++tt) {
            af[tt]  = *(const bf16x8*)&Asl[(wm + tt * 16 + l16) * 40 + quad * 8];
            bfr[tt] = *(const bf16x8*)&Bsl[(wn + tt * 16 + l16) * 40 + quad * 8];
        }
        #pragma unroll
        for (int mt = 0; mt < 4; ++mt)
            #pragma unroll
            for (int nt = 0; nt < 4; ++nt)
                acc[mt][nt] = __builtin_amdgcn_mfma_f32_16x16x32_bf16(
                    af[mt], bfr[nt], acc[mt][nt], 0, 0, 0);
        __syncthreads();
    }
    float w5r[4][3], b4v[4];
    #pragma unroll
    for (int nt = 0; nt < 4; ++nt) {
        int col = nbase + wn + nt * 16 + l16;
        b4v[nt] = b4[col];
        w5r[nt][0] = W5[col * 3 + 0];
        w5r[nt][1] = W5[col * 3 + 1];
        w5r[nt][2] = W5[col * 3 + 2];
    }
    #pragma unroll
    for (int mt = 0; mt < 4; ++mt) {
        #pragma unroll
        for (int r = 0; r < 4; ++r) {
            int row = mbase + wm + mt * 16 + quad * 4 + r;
            float p0 = 0.f, p1 = 0.f, p2 = 0.f;
            #pragma unroll
            for (int nt = 0; nt < 4; ++nt) {
                float h = fmaxf(acc[mt][nt][r] + b4v[nt], 0.f);
                p0 += h * w5r[nt][0];
                p1 += h * w5r[nt][1];
                p2 += h * w5r[nt][2];
            }
            #pragma unroll
            for (int m = 8; m; m >>= 1) {
                p0 += __shfl_xor(p0, m);
                p1 += __shfl_xor(p1, m);
                p2 += __shfl_xor(p2, m);
            }
            if (l16 == 0 && row < M) {
                atomicAdd(&out[row * 3 + 0], p0);
                atomicAdd(&out[row * 3 + 1], p1);
                atomicAdd(&out[row * 3 + 2], p2);
            }
        }
    }
}

__global__ void fallback_copy_kernel(const float* __restrict__ x, float* __restrict__ out) {
    int t = blockIdx.x * blockDim.x + threadIdx.x;
    if (t < NN * 3) out[t] = x[t];
}

// ---------------- launcher ----------------

extern "C" void kernel_launch(void* const* d_in, const int* in_sizes, int n_in,
                              void* d_out, int out_size, void* d_ws, size_t ws_size,
                              hipStream_t stream) {
    const float* x  = (const float*)d_in[0];
    const int*   ei = (const int*)d_in[1];
    const float* W1 = (const float*)d_in[2];
    const float* b1 = (const float*)d_in[3];
    const float* W2 = (const float*)d_in[4];
    const float* b2 = (const float*)d_in[5];
    const float* W3 = (const float*)d_in[6];
    const float* b3 = (const float*)d_in[7];
    const float* W4 = (const float*)d_in[8];
    const float* b4 = (const float*)d_in[9];
    const float* W5 = (const float*)d_in[10];
    const float* b5 = (const float*)d_in[11];
    float* out = (float*)d_out;

    char* p = (char*)d_ws;
    auto alloc = [&](size_t bytes) -> void* {
        void* r = (void*)p;
        p += (bytes + 255) & ~(size_t)255;
        return r;
    };
    int* deg      = (int*)alloc((size_t)NN * 4);
    int* rowstart = (int*)alloc((size_t)(NN + 1) * 4);
    int* cursor   = (int*)alloc((size_t)NN * 4);
    int* csr      = (int*)alloc((size_t)NE * 4);
    unsigned short* Bt2 = (unsigned short*)alloc(256 * 64 * 2);
    unsigned short* Bt3 = (unsigned short*)alloc(1024 * 128 * 2);
    unsigned short* W4t = (unsigned short*)alloc(256 * 512 * 2);
    unsigned short* x1 = (unsigned short*)alloc((size_t)NN * 64 * 2);
    unsigned short* x2 = (unsigned short*)alloc((size_t)NN * 128 * 2);
    unsigned short* x3 = (unsigned short*)alloc((size_t)NN * 512 * 2);
    unsigned short* as_slab = (unsigned short*)alloc((size_t)NN * 1024 * 2);  // as1/as2/as3
    size_t need = (size_t)(p - (char*)d_ws);
    if (ws_size < need) {
        fallback_copy_kernel<<<(NN * 3 + 255) / 256, 256, 0, stream>>>(x, out);
        return;
    }

    const int* src = ei;        // edge_index[0]
    const int* dst = ei + NE;   // edge_index[1]

    // out = x + b5 (final GEMM accumulates via atomics)
    init_out_kernel<<<(NN * 3 + 255) / 256, 256, 0, stream>>>(x, b5, out);

    // CSR by dst (graph static across all 3 convs)
    hipMemsetAsync(deg, 0, (size_t)NN * 4, stream);
    hist_kernel<<<(NE + 255) / 256, 256, 0, stream>>>(dst, deg);
    scan_kernel<<<1, 1024, 0, stream>>>(deg, rowstart, cursor);
    scatter_kernel<<<(NE + 255) / 256, 256, 0, stream>>>(src, dst, rowstart, cursor, csr);

    // all weight prep in one dispatch
    prep_all_kernel<<<800, 256, 0, stream>>>(W2, W3, W4, Bt2, Bt3, W4t);

    // conv1: as1 = [a1|s1] from x; x1 = relu(a1 + max_j s1[j])
    conv1_as_kernel<<<NN * 128 / 256, 256, 0, stream>>>(x, W1, b1, as_slab);
    edge_sliced_kernel<64, 2><<<dim3(2 * 12500, 1), 256, 0, stream>>>(
        as_slab, rowstart, csr, x1);

    // conv2: as2 = x1 @ [Wtb2|Wb2] (+b2 on a-half); x2 = relu(a2 + max s2)
    mfma_gemm_kernel<<<dim3(2, 391), 256, 0, stream>>>(
        x1, Bt2, b2, 128, as_slab, NN, 256, 64);
    edge_sliced_kernel<128, 4><<<dim3(4 * 12500, 1), 256, 0, stream>>>(
        as_slab, rowstart, csr, x2);

    // conv3: as3 = x2 @ [Wtb3|Wb3] (+b3 on a-half); x3 = relu(a3 + max s3)
    mfma_gemm_kernel<<<dim3(8, 391), 256, 0, stream>>>(
        x2, Bt3, b3, 512, as_slab, NN, 1024, 128);
    edge_sliced_kernel<512, 16><<<dim3(8 * 12500, 2), 256, 0, stream>>>(
        as_slab, rowstart, csr, x3);

    // out += relu(x3@W4 + b4) @ W5   (fused, no h4 materialization)
    mfma_gemm_w5_kernel<<<dim3(2, 391), 256, 0, stream>>>(
        x3, W4t, b4, W5, out, NN, 512);
}

// Round 8
// 628.734 us; speedup vs baseline: 1.3777x; 1.3777x over previous
//
#include <hip/hip_runtime.h>

static constexpr int NN = 50000;
static constexpr int NE = 1000000;

typedef short bf16x8 __attribute__((ext_vector_type(8)));
typedef float f32x4 __attribute__((ext_vector_type(4)));

__device__ inline float bf2f_raw(unsigned short u) {
    return __uint_as_float(((unsigned int)u) << 16);
}
__device__ inline unsigned short f2bf(float f) {
    unsigned int u = __float_as_uint(f);
    u += 0x7fffu + ((u >> 16) & 1u);
    return (unsigned short)(u >> 16);
}
__device__ inline void fmax2(float& a0, float& a1, unsigned int v) {
    a0 = fmaxf(a0, bf2f_raw((unsigned short)(v & 0xffffu)));
    a1 = fmaxf(a1, bf2f_raw((unsigned short)(v >> 16)));
}
__device__ inline unsigned int pack2(float f0, float f1) {
    return (unsigned int)f2bf(f0) | ((unsigned int)f2bf(f1) << 16);
}
__device__ inline unsigned int addrelu2(unsigned int a, float t0, float t1) {
    float f0 = fmaxf(bf2f_raw((unsigned short)(a & 0xffffu)) + t0, 0.f);
    float f1 = fmaxf(bf2f_raw((unsigned short)(a >> 16)) + t1, 0.f);
    return pack2(f0, f1);
}

// ---------------- merged setup: conv1_as + out-init + deg-zero + all weight prep ----------------
// ranges: [0,6.4M) conv1_as ; [6.4M,+150k) out=x+b5 ; [+50k) deg=0 ;
//         [+8192) Bt2 ; [+65536) Bt3 ; [+131072) W4t

__global__ void setup_kernel(const float* __restrict__ x, const float* __restrict__ W1,
                             const float* __restrict__ b1, const float* __restrict__ b5,
                             const float* __restrict__ W2, const float* __restrict__ W3,
                             const float* __restrict__ W4,
                             unsigned short* __restrict__ as1, float* __restrict__ out,
                             int* __restrict__ deg,
                             unsigned short* __restrict__ Bt2,
                             unsigned short* __restrict__ Bt3,
                             unsigned short* __restrict__ W4t) {
    int t = blockIdx.x * blockDim.x + threadIdx.x;
    if (t < NN * 128) {
        // conv1: as1[i] = [a1(64) | s1(64)],  a = x@(Wt-Wb)+b1, s = x@Wb  (W1 is [6][64])
        int i = t >> 7, c = t & 127;
        float x0 = x[i * 3 + 0], x1 = x[i * 3 + 1], x2 = x[i * 3 + 2];
        float v;
        if (c < 64) {
            v = x0 * (W1[c] - W1[192 + c]) + x1 * (W1[64 + c] - W1[256 + c]) +
                x2 * (W1[128 + c] - W1[320 + c]) + b1[c];
        } else {
            int cs = c - 64;
            v = x0 * W1[192 + cs] + x1 * W1[256 + cs] + x2 * W1[320 + cs];
        }
        as1[t] = f2bf(v);
        return;
    }
    t -= NN * 128;
    if (t < NN * 3) { out[t] = x[t] + b5[t % 3]; return; }
    t -= NN * 3;
    if (t < NN) { deg[t] = 0; return; }
    t -= NN;
    if (t < 8192) {  // W2 split (64x128)
        int k = t / 128, c = t % 128;
        float wt = W2[k * 128 + c];
        float wb = W2[(64 + k) * 128 + c];
        Bt2[c * 64 + k] = f2bf(wt - wb);
        Bt2[(128 + c) * 64 + k] = f2bf(wb);
        return;
    }
    t -= 8192;
    if (t < 65536) {  // W3 split (128x512)
        int k = t / 512, c = t % 512;
        float wt = W3[k * 512 + c];
        float wb = W3[(128 + k) * 512 + c];
        Bt3[c * 128 + k] = f2bf(wt - wb);
        Bt3[(512 + c) * 128 + k] = f2bf(wb);
        return;
    }
    t -= 65536;
    if (t < 131072) {  // W4 transpose (512x256)
        int k = t / 256, n = t % 256;
        W4t[n * 512 + k] = f2bf(W4[k * 256 + n]);
    }
}

// ---------------- CSR build ----------------

__global__ void hist_kernel(const int* __restrict__ dst, int* __restrict__ deg) {
    int e = blockIdx.x * blockDim.x + threadIdx.x;
    if (e < NE) atomicAdd(&deg[dst[e]], 1);
}

// single-block scan, register-resident
__global__ __launch_bounds__(1024) void scan_kernel(const int* __restrict__ deg,
                                                    int* __restrict__ rowstart,
                                                    int* __restrict__ cursor) {
    __shared__ int wave_sums[16];
    constexpr int CH = (NN + 1023) / 1024;  // 49
    int tid = threadIdx.x;
    int lane = tid & 63;
    int wave = tid >> 6;
    for (int i = tid; i < NN; i += 1024) cursor[i] = 0;
    int base = tid * CH;
    int vals[CH];
    int sum = 0;
    #pragma unroll
    for (int i = 0; i < CH; ++i) {
        int idx = base + i;
        vals[i] = (idx < NN) ? deg[idx] : 0;
        sum += vals[i];
    }
    int x = sum;
    #pragma unroll
    for (int off = 1; off < 64; off <<= 1) {
        int y = __shfl_up(x, off);
        if (lane >= off) x += y;
    }
    if (lane == 63) wave_sums[wave] = x;
    __syncthreads();
    if (wave == 0 && lane < 16) {
        int s = wave_sums[lane];
        #pragma unroll
        for (int off = 1; off < 16; off <<= 1) {
            int y = __shfl_up(s, off);
            if (lane >= off) s += y;
        }
        wave_sums[lane] = s;
    }
    __syncthreads();
    int run = (wave ? wave_sums[wave - 1] : 0) + x - sum;
    #pragma unroll
    for (int i = 0; i < CH; ++i) {
        int idx = base + i;
        if (idx < NN) rowstart[idx] = run;
        run += vals[i];
    }
    if (tid == 1023) rowstart[NN] = run;
}

__global__ void scatter_kernel(const int* __restrict__ src, const int* __restrict__ dst,
                               const int* __restrict__ rowstart, int* __restrict__ cursor,
                               int* __restrict__ csr) {
    int e = blockIdx.x * blockDim.x + threadIdx.x;
    if (e < NE) {
        int d = dst[e];
        int pos = atomicAdd(&cursor[d], 1);
        csr[rowstart[d] + pos] = src[e];
    }
}

// ---------------- conv1 fused edge-max + epilogue (C=64, as rows [a(64)|s(64)]) ----------------

__global__ __launch_bounds__(256) void edge_fused_conv1_kernel(
    const unsigned short* __restrict__ as, const int* __restrict__ rowstart,
    const int* __restrict__ csr, unsigned short* __restrict__ x1) {
    int wid = (blockIdx.x * 256 + threadIdx.x) >> 6;
    int lane = threadIdx.x & 63;
    if (wid >= NN) return;
    int e0 = __builtin_amdgcn_readfirstlane(rowstart[wid]);
    int e1 = __builtin_amdgcn_readfirstlane(rowstart[wid + 1]);
    int h = lane >> 5, c0 = (lane & 31) * 2;
    float t0 = -INFINITY, t1 = -INFINITY;
    const unsigned short* sb = as + 64 + c0;
    int nedge = e1 - e0;
    for (int base = 0; base < nedge; base += 64) {
        int rem = nedge - base;
        int myj = csr[(lane < rem) ? (e0 + base + lane) : e0];
        int cnt = rem < 64 ? rem : 64;
        int cp = (cnt + 7) & ~7;
        for (int q = 0; q < cp; q += 8) {
            int j0 = __shfl(myj, q + 0 + h);
            int j1 = __shfl(myj, q + 2 + h);
            int j2 = __shfl(myj, q + 4 + h);
            int j3 = __shfl(myj, q + 6 + h);
            unsigned int v0 = *(const unsigned int*)(sb + (size_t)j0 * 128);
            unsigned int v1 = *(const unsigned int*)(sb + (size_t)j1 * 128);
            unsigned int v2 = *(const unsigned int*)(sb + (size_t)j2 * 128);
            unsigned int v3 = *(const unsigned int*)(sb + (size_t)j3 * 128);
            fmax2(t0, t1, v0);
            fmax2(t0, t1, v1);
            fmax2(t0, t1, v2);
            fmax2(t0, t1, v3);
        }
    }
    t0 = fmaxf(t0, __shfl_xor(t0, 32));
    t1 = fmaxf(t1, __shfl_xor(t1, 32));
    if (h == 0) {
        unsigned int av = *(const unsigned int*)(as + (size_t)wid * 128 + c0);
        *(unsigned int*)(x1 + (size_t)wid * 64 + c0) = addrelu2(av, t0, t1);
    }
}

// ---------------- fused edge-max + epilogue, C=128 (as rows [a(128)|s(128)]) ----------------

__global__ __launch_bounds__(256) void edge_fused128_kernel(
    const unsigned short* __restrict__ as, const int* __restrict__ rowstart,
    const int* __restrict__ csr, unsigned short* __restrict__ xout) {
    int wid = (blockIdx.x * 256 + threadIdx.x) >> 6;
    int lane = threadIdx.x & 63;
    if (wid >= NN) return;
    int e0 = __builtin_amdgcn_readfirstlane(rowstart[wid]);
    int e1 = __builtin_amdgcn_readfirstlane(rowstart[wid + 1]);
    float t0 = -INFINITY, t1 = -INFINITY;
    const unsigned short* sb = as + 128 + (size_t)lane * 2;
    int nedge = e1 - e0;
    for (int base = 0; base < nedge; base += 64) {
        int rem = nedge - base;
        int myj = csr[(lane < rem) ? (e0 + base + lane) : e0];
        int cnt = rem < 64 ? rem : 64;
        int cp = (cnt + 7) & ~7;
        for (int q = 0; q < cp; q += 8) {
            int j0 = __shfl(myj, q + 0), j1 = __shfl(myj, q + 1);
            int j2 = __shfl(myj, q + 2), j3 = __shfl(myj, q + 3);
            int j4 = __shfl(myj, q + 4), j5 = __shfl(myj, q + 5);
            int j6 = __shfl(myj, q + 6), j7 = __shfl(myj, q + 7);
            unsigned int v0 = *(const unsigned int*)(sb + (size_t)j0 * 256);
            unsigned int v1 = *(const unsigned int*)(sb + (size_t)j1 * 256);
            unsigned int v2 = *(const unsigned int*)(sb + (size_t)j2 * 256);
            unsigned int v3 = *(const unsigned int*)(sb + (size_t)j3 * 256);
            unsigned int v4 = *(const unsigned int*)(sb + (size_t)j4 * 256);
            unsigned int v5 = *(const unsigned int*)(sb + (size_t)j5 * 256);
            unsigned int v6 = *(const unsigned int*)(sb + (size_t)j6 * 256);
            unsigned int v7 = *(const unsigned int*)(sb + (size_t)j7 * 256);
            fmax2(t0, t1, v0); fmax2(t0, t1, v1);
            fmax2(t0, t1, v2); fmax2(t0, t1, v3);
            fmax2(t0, t1, v4); fmax2(t0, t1, v5);
            fmax2(t0, t1, v6); fmax2(t0, t1, v7);
        }
    }
    unsigned int av = *(const unsigned int*)(as + (size_t)wid * 256 + lane * 2);
    *(unsigned int*)(xout + (size_t)wid * 128 + lane * 2) = addrelu2(av, t0, t1);
}

// ---------------- fused edge-max + epilogue, C=512 (as rows [a(512)|s(512)]) ----------------

__global__ __launch_bounds__(256) void edge_fused512_kernel(
    const unsigned short* __restrict__ as, const int* __restrict__ rowstart,
    const int* __restrict__ csr, unsigned short* __restrict__ xout) {
    int wid = (blockIdx.x * 256 + threadIdx.x) >> 6;
    int lane = threadIdx.x & 63;
    if (wid >= NN) return;
    int e0 = __builtin_amdgcn_readfirstlane(rowstart[wid]);
    int e1 = __builtin_amdgcn_readfirstlane(rowstart[wid + 1]);
    float acc[8];
    #pragma unroll
    for (int v = 0; v < 8; ++v) acc[v] = -INFINITY;
    const unsigned short* sb = as + 512 + (size_t)lane * 8;
    int nedge = e1 - e0;
    for (int base = 0; base < nedge; base += 64) {
        int rem = nedge - base;
        int myj = csr[(lane < rem) ? (e0 + base + lane) : e0];
        int cnt = rem < 64 ? rem : 64;
        int cp = (cnt + 3) & ~3;
        for (int q = 0; q < cp; q += 4) {
            int j0 = __shfl(myj, q + 0), j1 = __shfl(myj, q + 1);
            int j2 = __shfl(myj, q + 2), j3 = __shfl(myj, q + 3);
            uint4 v0 = *(const uint4*)(sb + (size_t)j0 * 1024);
            uint4 v1 = *(const uint4*)(sb + (size_t)j1 * 1024);
            uint4 v2 = *(const uint4*)(sb + (size_t)j2 * 1024);
            uint4 v3 = *(const uint4*)(sb + (size_t)j3 * 1024);
            fmax2(acc[0], acc[1], v0.x); fmax2(acc[2], acc[3], v0.y);
            fmax2(acc[4], acc[5], v0.z); fmax2(acc[6], acc[7], v0.w);
            fmax2(acc[0], acc[1], v1.x); fmax2(acc[2], acc[3], v1.y);
            fmax2(acc[4], acc[5], v1.z); fmax2(acc[6], acc[7], v1.w);
            fmax2(acc[0], acc[1], v2.x); fmax2(acc[2], acc[3], v2.y);
            fmax2(acc[4], acc[5], v2.z); fmax2(acc[6], acc[7], v2.w);
            fmax2(acc[0], acc[1], v3.x); fmax2(acc[2], acc[3], v3.y);
            fmax2(acc[4], acc[5], v3.z); fmax2(acc[6], acc[7], v3.w);
        }
    }
    uint4 av = *(const uint4*)(as + (size_t)wid * 1024 + lane * 8);
    uint4 o;
    o.x = addrelu2(av.x, acc[0], acc[1]);
    o.y = addrelu2(av.y, acc[2], acc[3]);
    o.z = addrelu2(av.z, acc[4], acc[5]);
    o.w = addrelu2(av.w, acc[6], acc[7]);
    *(uint4*)(xout + (size_t)wid * 512 + lane * 8) = o;
}

// ---------------- MFMA GEMM: C_bf16 = A_bf16[M,K] @ B (+bias on cols < bias_n) ----------------

__global__ __launch_bounds__(256) void mfma_gemm_kernel(
    const unsigned short* __restrict__ A, const unsigned short* __restrict__ Bt,
    const float* __restrict__ bias, int bias_n,
    unsigned short* __restrict__ C, int M, int N, int K) {
    __shared__ __align__(16) unsigned short Asl[128 * 40];
    __shared__ __align__(16) unsigned short Bsl[128 * 40];
    int tid = threadIdx.x;
    int mbase = blockIdx.y * 128, nbase = blockIdx.x * 128;
    int wave = tid >> 6, lane = tid & 63;
    int wm = (wave >> 1) * 64, wn = (wave & 1) * 64;
    int quad = lane >> 4, l16 = lane & 15;
    f32x4 acc[4][4] = {};
    for (int kb = 0; kb < K; kb += 32) {
        #pragma unroll
        for (int h = 0; h < 2; ++h) {
            int c = tid + h * 256;
            int r = c >> 2, kk = (c & 3) * 8;
            uint4 va = make_uint4(0u, 0u, 0u, 0u);
            int gr = mbase + r;
            if (gr < M) va = *(const uint4*)&A[(size_t)gr * K + kb + kk];
            *(uint4*)&Asl[r * 40 + kk] = va;
            uint4 vb = *(const uint4*)&Bt[(size_t)(nbase + r) * K + kb + kk];
            *(uint4*)&Bsl[r * 40 + kk] = vb;
        }
        __syncthreads();
        bf16x8 af[4], bfr[4];
        #pragma unroll
        for (int tt = 0; tt < 4; ++tt) {
            af[tt]  = *(const bf16x8*)&Asl[(wm + tt * 16 + l16) * 40 + quad * 8];
            bfr[tt] = *(const bf16x8*)&Bsl[(wn + tt * 16 + l16) * 40 + quad * 8];
        }
        #pragma unroll
        for (int mt = 0; mt < 4; ++mt)
            #pragma unroll
            for (int nt = 0; nt < 4; ++nt)
                acc[mt][nt] = __builtin_amdgcn_mfma_f32_16x16x32_bf16(
                    af[mt], bfr[nt], acc[mt][nt], 0, 0, 0);
        __syncthreads();
    }
    #pragma unroll
    for (int mt = 0; mt < 4; ++mt) {
        #pragma unroll
        for (int r = 0; r < 4; ++r) {
            int row = mbase + wm + mt * 16 + quad * 4 + r;
            if (row >= M) continue;
            #pragma unroll
            for (int nt = 0; nt < 4; ++nt) {
                int col = nbase + wn + nt * 16 + l16;
                float v = acc[mt][nt][r];
                if (col < bias_n) v += bias[col];
                C[(size_t)row * N + col] = f2bf(v);
            }
        }
    }
}

// ---------------- fused last stage: out += relu(x3@W4 + b4) @ W5 ----------------

__global__ __launch_bounds__(256) void mfma_gemm_w5_kernel(
    const unsigned short* __restrict__ A, const unsigned short* __restrict__ Bt,
    const float* __restrict__ b4, const float* __restrict__ W5,
    float* __restrict__ out, int M, int K) {
    __shared__ __align__(16) unsigned short Asl[128 * 40];
    __shared__ __align__(16) unsigned short Bsl[128 * 40];
    int tid = threadIdx.x;
    int mbase = blockIdx.y * 128, nbase = blockIdx.x * 128;
    int wave = tid >> 6, lane = tid & 63;
    int wm = (wave >> 1) * 64, wn = (wave & 1) * 64;
    int quad = lane >> 4, l16 = lane & 15;
    f32x4 acc[4][4] = {};
    for (int kb = 0; kb < K; kb += 32) {
        #pragma unroll
        for (int h = 0; h < 2; ++h) {
            int c = tid + h * 256;
            int r = c >> 2, kk = (c & 3) * 8;
            uint4 va = make_uint4(0u, 0u, 0u, 0u);
            int gr = mbase + r;
            if (gr < M) va = *(const uint4*)&A[(size_t)gr * K + kb + kk];
            *(uint4*)&Asl[r * 40 + kk] = va;
            uint4 vb = *(const uint4*)&Bt[(size_t)(nbase + r) * K + kb + kk];
            *(uint4*)&Bsl[r * 40 + kk] = vb;
        }
        __syncthreads();
        bf16x8 af[4], bfr[4];
        #pragma unroll
        for (int tt = 0; tt < 4; ++tt) {
            af[tt]  = *(const bf16x8*)&Asl[(wm + tt * 16 + l16) * 40 + quad * 8];
            bfr[tt] = *(const bf16x8*)&Bsl[(wn + tt * 16 + l16) * 40 + quad * 8];
        }
        #pragma unroll
        for (int mt = 0; mt < 4; ++mt)
            #pragma unroll
            for (int nt = 0; nt < 4; ++nt)
                acc[mt][nt] = __builtin_amdgcn_mfma_f32_16x16x32_bf16(
                    af[mt], bfr[nt], acc[mt][nt], 0, 0, 0);
        __syncthreads();
    }
    float w5r[4][3], b4v[4];
    #pragma unroll
    for (int nt = 0; nt < 4; ++nt) {
        int col = nbase + wn + nt * 16 + l16;
        b4v[nt] = b4[col];
        w5r[nt][0] = W5[col * 3 + 0];
        w5r[nt][1] = W5[col * 3 + 1];
        w5r[nt][2] = W5[col * 3 + 2];
    }
    #pragma unroll
    for (int mt = 0; mt < 4; ++mt) {
        #pragma unroll
        for (int r = 0; r < 4; ++r) {
            int row = mbase + wm + mt * 16 + quad * 4 + r;
            float p0 = 0.f, p1 = 0.f, p2 = 0.f;
            #pragma unroll
            for (int nt = 0; nt < 4; ++nt) {
                float h = fmaxf(acc[mt][nt][r] + b4v[nt], 0.f);
                p0 += h * w5r[nt][0];
                p1 += h * w5r[nt][1];
                p2 += h * w5r[nt][2];
            }
            #pragma unroll
            for (int m = 8; m; m >>= 1) {
                p0 += __shfl_xor(p0, m);
                p1 += __shfl_xor(p1, m);
                p2 += __shfl_xor(p2, m);
            }
            if (l16 == 0 && row < M) {
                atomicAdd(&out[row * 3 + 0], p0);
                atomicAdd(&out[row * 3 + 1], p1);
                atomicAdd(&out[row * 3 + 2], p2);
            }
        }
    }
}

__global__ void fallback_copy_kernel(const float* __restrict__ x, float* __restrict__ out) {
    int t = blockIdx.x * blockDim.x + threadIdx.x;
    if (t < NN * 3) out[t] = x[t];
}

// ---------------- launcher ----------------

extern "C" void kernel_launch(void* const* d_in, const int* in_sizes, int n_in,
                              void* d_out, int out_size, void* d_ws, size_t ws_size,
                              hipStream_t stream) {
    const float* x  = (const float*)d_in[0];
    const int*   ei = (const int*)d_in[1];
    const float* W1 = (const float*)d_in[2];
    const float* b1 = (const float*)d_in[3];
    const float* W2 = (const float*)d_in[4];
    const float* b2 = (const float*)d_in[5];
    const float* W3 = (const float*)d_in[6];
    const float* b3 = (const float*)d_in[7];
    const float* W4 = (const float*)d_in[8];
    const float* b4 = (const float*)d_in[9];
    const float* W5 = (const float*)d_in[10];
    const float* b5 = (const float*)d_in[11];
    float* out = (float*)d_out;

    char* p = (char*)d_ws;
    auto alloc = [&](size_t bytes) -> void* {
        void* r = (void*)p;
        p += (bytes + 255) & ~(size_t)255;
        return r;
    };
    int* deg      = (int*)alloc((size_t)NN * 4);
    int* rowstart = (int*)alloc((size_t)(NN + 1) * 4);
    int* cursor   = (int*)alloc((size_t)NN * 4);
    int* csr      = (int*)alloc((size_t)NE * 4);
    unsigned short* Bt2 = (unsigned short*)alloc(256 * 64 * 2);
    unsigned short* Bt3 = (unsigned short*)alloc(1024 * 128 * 2);
    unsigned short* W4t = (unsigned short*)alloc(256 * 512 * 2);
    unsigned short* x1 = (unsigned short*)alloc((size_t)NN * 64 * 2);
    unsigned short* x2 = (unsigned short*)alloc((size_t)NN * 128 * 2);
    unsigned short* x3 = (unsigned short*)alloc((size_t)NN * 512 * 2);
    unsigned short* as_slab = (unsigned short*)alloc((size_t)NN * 1024 * 2);  // as1/as2/as3
    size_t need = (size_t)(p - (char*)d_ws);
    if (ws_size < need) {
        fallback_copy_kernel<<<(NN * 3 + 255) / 256, 256, 0, stream>>>(x, out);
        return;
    }

    const int* src = ei;        // edge_index[0]
    const int* dst = ei + NE;   // edge_index[1]

    // merged setup: conv1_as + out=x+b5 + deg=0 + weight prep (one dispatch)
    constexpr int SETUP_T = NN * 128 + NN * 3 + NN + 8192 + 65536 + 131072;
    setup_kernel<<<(SETUP_T + 255) / 256, 256, 0, stream>>>(
        x, W1, b1, b5, W2, W3, W4, as_slab, out, deg, Bt2, Bt3, W4t);

    // CSR by dst (graph static across all 3 convs)
    hist_kernel<<<(NE + 255) / 256, 256, 0, stream>>>(dst, deg);
    scan_kernel<<<1, 1024, 0, stream>>>(deg, rowstart, cursor);
    scatter_kernel<<<(NE + 255) / 256, 256, 0, stream>>>(src, dst, rowstart, cursor, csr);

    // conv1: x1 = relu(a1 + max_j s1[j])
    edge_fused_conv1_kernel<<<12500, 256, 0, stream>>>(as_slab, rowstart, csr, x1);

    // conv2: as2 = x1 @ [Wtb2|Wb2] (+b2 on a-half); x2 = relu(a2 + max s2)
    mfma_gemm_kernel<<<dim3(2, 391), 256, 0, stream>>>(
        x1, Bt2, b2, 128, as_slab, NN, 256, 64);
    edge_fused128_kernel<<<12500, 256, 0, stream>>>(as_slab, rowstart, csr, x2);

    // conv3: as3 = x2 @ [Wtb3|Wb3] (+b3 on a-half); x3 = relu(a3 + max s3)
    mfma_gemm_kernel<<<dim3(8, 391), 256, 0, stream>>>(
        x2, Bt3, b3, 512, as_slab, NN, 1024, 128);
    edge_fused512_kernel<<<12500, 256, 0, stream>>>(as_slab, rowstart, csr, x3);

    // out += relu(x3@W4 + b4) @ W5   (fused, no h4 materialization)
    mfma_gemm_w5_kernel<<<dim3(2, 391), 256, 0, stream>>>(
        x3, W4t, b4, W5, out, NN, 512);
}

// Round 9
// 618.500 us; speedup vs baseline: 1.4005x; 1.0165x over previous
//
#include <hip/hip_runtime.h>

static constexpr int NN = 50000;
static constexpr int NE = 1000000;

typedef short bf16x8 __attribute__((ext_vector_type(8)));
typedef float f32x4 __attribute__((ext_vector_type(4)));

__device__ inline float bf2f_raw(unsigned short u) {
    return __uint_as_float(((unsigned int)u) << 16);
}
__device__ inline unsigned short f2bf(float f) {
    unsigned int u = __float_as_uint(f);
    u += 0x7fffu + ((u >> 16) & 1u);
    return (unsigned short)(u >> 16);
}
__device__ inline void fmax2(float& a0, float& a1, unsigned int v) {
    a0 = fmaxf(a0, bf2f_raw((unsigned short)(v & 0xffffu)));
    a1 = fmaxf(a1, bf2f_raw((unsigned short)(v >> 16)));
}
__device__ inline unsigned int pack2(float f0, float f1) {
    return (unsigned int)f2bf(f0) | ((unsigned int)f2bf(f1) << 16);
}
__device__ inline unsigned int addrelu2(unsigned int a, float t0, float t1) {
    float f0 = fmaxf(bf2f_raw((unsigned short)(a & 0xffffu)) + t0, 0.f);
    float f1 = fmaxf(bf2f_raw((unsigned short)(a >> 16)) + t1, 0.f);
    return pack2(f0, f1);
}

// ---------------- merged setup: conv1_as + out-init + deg-zero + cursor-zero + weight prep --------

__global__ void setup_kernel(const float* __restrict__ x, const float* __restrict__ W1,
                             const float* __restrict__ b1, const float* __restrict__ b5,
                             const float* __restrict__ W2, const float* __restrict__ W3,
                             const float* __restrict__ W4,
                             unsigned short* __restrict__ as1, float* __restrict__ out,
                             int* __restrict__ deg, int* __restrict__ cursor,
                             unsigned short* __restrict__ Bt2,
                             unsigned short* __restrict__ Bt3,
                             unsigned short* __restrict__ W4t) {
    int t = blockIdx.x * blockDim.x + threadIdx.x;
    if (t < NN * 128) {
        // conv1: as1[i] = [a1(64) | s1(64)],  a = x@(Wt-Wb)+b1, s = x@Wb  (W1 is [6][64])
        int i = t >> 7, c = t & 127;
        float x0 = x[i * 3 + 0], x1 = x[i * 3 + 1], x2 = x[i * 3 + 2];
        float v;
        if (c < 64) {
            v = x0 * (W1[c] - W1[192 + c]) + x1 * (W1[64 + c] - W1[256 + c]) +
                x2 * (W1[128 + c] - W1[320 + c]) + b1[c];
        } else {
            int cs = c - 64;
            v = x0 * W1[192 + cs] + x1 * W1[256 + cs] + x2 * W1[320 + cs];
        }
        as1[t] = f2bf(v);
        return;
    }
    t -= NN * 128;
    if (t < NN * 3) { out[t] = x[t] + b5[t % 3]; return; }
    t -= NN * 3;
    if (t < NN) { deg[t] = 0; return; }
    t -= NN;
    if (t < NN) { cursor[t] = 0; return; }
    t -= NN;
    if (t < 8192) {  // W2 split (64x128)
        int k = t / 128, c = t % 128;
        float wt = W2[k * 128 + c];
        float wb = W2[(64 + k) * 128 + c];
        Bt2[c * 64 + k] = f2bf(wt - wb);
        Bt2[(128 + c) * 64 + k] = f2bf(wb);
        return;
    }
    t -= 8192;
    if (t < 65536) {  // W3 split (128x512)
        int k = t / 512, c = t % 512;
        float wt = W3[k * 512 + c];
        float wb = W3[(128 + k) * 512 + c];
        Bt3[c * 128 + k] = f2bf(wt - wb);
        Bt3[(512 + c) * 128 + k] = f2bf(wb);
        return;
    }
    t -= 65536;
    if (t < 131072) {  // W4 transpose (512x256)
        int k = t / 256, n = t % 256;
        W4t[n * 512 + k] = f2bf(W4[k * 256 + n]);
    }
}

// ---------------- CSR build ----------------

__global__ void hist_kernel(const int* __restrict__ dst, int* __restrict__ deg) {
    int e = blockIdx.x * blockDim.x + threadIdx.x;
    if (e < NE) atomicAdd(&deg[dst[e]], 1);
}

// single-block scan, register-resident
__global__ __launch_bounds__(1024) void scan_kernel(const int* __restrict__ deg,
                                                    int* __restrict__ rowstart) {
    __shared__ int wave_sums[16];
    constexpr int CH = (NN + 1023) / 1024;  // 49
    int tid = threadIdx.x;
    int lane = tid & 63;
    int wave = tid >> 6;
    int base = tid * CH;
    int vals[CH];
    int sum = 0;
    #pragma unroll
    for (int i = 0; i < CH; ++i) {
        int idx = base + i;
        vals[i] = (idx < NN) ? deg[idx] : 0;
        sum += vals[i];
    }
    int x = sum;
    #pragma unroll
    for (int off = 1; off < 64; off <<= 1) {
        int y = __shfl_up(x, off);
        if (lane >= off) x += y;
    }
    if (lane == 63) wave_sums[wave] = x;
    __syncthreads();
    if (wave == 0 && lane < 16) {
        int s = wave_sums[lane];
        #pragma unroll
        for (int off = 1; off < 16; off <<= 1) {
            int y = __shfl_up(s, off);
            if (lane >= off) s += y;
        }
        wave_sums[lane] = s;
    }
    __syncthreads();
    int run = (wave ? wave_sums[wave - 1] : 0) + x - sum;
    #pragma unroll
    for (int i = 0; i < CH; ++i) {
        int idx = base + i;
        if (idx < NN) rowstart[idx] = run;
        run += vals[i];
    }
    if (tid == 1023) rowstart[NN] = run;
}

__global__ void scatter_kernel(const int* __restrict__ src, const int* __restrict__ dst,
                               const int* __restrict__ rowstart, int* __restrict__ cursor,
                               int* __restrict__ csr) {
    int e = blockIdx.x * blockDim.x + threadIdx.x;
    if (e < NE) {
        int d = dst[e];
        int pos = atomicAdd(&cursor[d], 1);
        csr[rowstart[d] + pos] = src[e];
    }
}

// ---------------- conv1 fused edge-max + epilogue (C=64, as rows [a(64)|s(64)]) ----------------

__global__ __launch_bounds__(256) void edge_fused_conv1_kernel(
    const unsigned short* __restrict__ as, const int* __restrict__ rowstart,
    const int* __restrict__ csr, unsigned short* __restrict__ x1) {
    int wid = (blockIdx.x * 256 + threadIdx.x) >> 6;
    int lane = threadIdx.x & 63;
    if (wid >= NN) return;
    int e0 = __builtin_amdgcn_readfirstlane(rowstart[wid]);
    int e1 = __builtin_amdgcn_readfirstlane(rowstart[wid + 1]);
    int h = lane >> 5, c0 = (lane & 31) * 2;
    float t0 = -INFINITY, t1 = -INFINITY;
    const unsigned short* sb = as + 64 + c0;
    int nedge = e1 - e0;
    for (int base = 0; base < nedge; base += 64) {
        int rem = nedge - base;
        int myj = csr[(lane < rem) ? (e0 + base + lane) : e0];
        int cnt = rem < 64 ? rem : 64;
        int cp = (cnt + 7) & ~7;
        for (int q = 0; q < cp; q += 8) {
            int j0 = __shfl(myj, q + 0 + h);
            int j1 = __shfl(myj, q + 2 + h);
            int j2 = __shfl(myj, q + 4 + h);
            int j3 = __shfl(myj, q + 6 + h);
            unsigned int v0 = *(const unsigned int*)(sb + (size_t)j0 * 128);
            unsigned int v1 = *(const unsigned int*)(sb + (size_t)j1 * 128);
            unsigned int v2 = *(const unsigned int*)(sb + (size_t)j2 * 128);
            unsigned int v3 = *(const unsigned int*)(sb + (size_t)j3 * 128);
            fmax2(t0, t1, v0);
            fmax2(t0, t1, v1);
            fmax2(t0, t1, v2);
            fmax2(t0, t1, v3);
        }
    }
    t0 = fmaxf(t0, __shfl_xor(t0, 32));
    t1 = fmaxf(t1, __shfl_xor(t1, 32));
    if (h == 0) {
        unsigned int av = *(const unsigned int*)(as + (size_t)wid * 128 + c0);
        *(unsigned int*)(x1 + (size_t)wid * 64 + c0) = addrelu2(av, t0, t1);
    }
}

// ---------------- fused edge-max + epilogue, C=128 (as rows [a(128)|s(128)]) ----------------

__global__ __launch_bounds__(256) void edge_fused128_kernel(
    const unsigned short* __restrict__ as, const int* __restrict__ rowstart,
    const int* __restrict__ csr, unsigned short* __restrict__ xout) {
    int wid = (blockIdx.x * 256 + threadIdx.x) >> 6;
    int lane = threadIdx.x & 63;
    if (wid >= NN) return;
    int e0 = __builtin_amdgcn_readfirstlane(rowstart[wid]);
    int e1 = __builtin_amdgcn_readfirstlane(rowstart[wid + 1]);
    float t0 = -INFINITY, t1 = -INFINITY;
    const unsigned short* sb = as + 128 + (size_t)lane * 2;
    int nedge = e1 - e0;
    for (int base = 0; base < nedge; base += 64) {
        int rem = nedge - base;
        int myj = csr[(lane < rem) ? (e0 + base + lane) : e0];
        int cnt = rem < 64 ? rem : 64;
        int cp = (cnt + 7) & ~7;
        for (int q = 0; q < cp; q += 8) {
            int j0 = __shfl(myj, q + 0), j1 = __shfl(myj, q + 1);
            int j2 = __shfl(myj, q + 2), j3 = __shfl(myj, q + 3);
            int j4 = __shfl(myj, q + 4), j5 = __shfl(myj, q + 5);
            int j6 = __shfl(myj, q + 6), j7 = __shfl(myj, q + 7);
            unsigned int v0 = *(const unsigned int*)(sb + (size_t)j0 * 256);
            unsigned int v1 = *(const unsigned int*)(sb + (size_t)j1 * 256);
            unsigned int v2 = *(const unsigned int*)(sb + (size_t)j2 * 256);
            unsigned int v3 = *(const unsigned int*)(sb + (size_t)j3 * 256);
            unsigned int v4 = *(const unsigned int*)(sb + (size_t)j4 * 256);
            unsigned int v5 = *(const unsigned int*)(sb + (size_t)j5 * 256);
            unsigned int v6 = *(const unsigned int*)(sb + (size_t)j6 * 256);
            unsigned int v7 = *(const unsigned int*)(sb + (size_t)j7 * 256);
            fmax2(t0, t1, v0); fmax2(t0, t1, v1);
            fmax2(t0, t1, v2); fmax2(t0, t1, v3);
            fmax2(t0, t1, v4); fmax2(t0, t1, v5);
            fmax2(t0, t1, v6); fmax2(t0, t1, v7);
        }
    }
    unsigned int av = *(const unsigned int*)(as + (size_t)wid * 256 + lane * 2);
    *(unsigned int*)(xout + (size_t)wid * 128 + lane * 2) = addrelu2(av, t0, t1);
}

// ---------------- fused edge-max + epilogue, C=512 (as rows [a(512)|s(512)]) ----------------

__global__ __launch_bounds__(256) void edge_fused512_kernel(
    const unsigned short* __restrict__ as, const int* __restrict__ rowstart,
    const int* __restrict__ csr, unsigned short* __restrict__ xout) {
    int wid = (blockIdx.x * 256 + threadIdx.x) >> 6;
    int lane = threadIdx.x & 63;
    if (wid >= NN) return;
    int e0 = __builtin_amdgcn_readfirstlane(rowstart[wid]);
    int e1 = __builtin_amdgcn_readfirstlane(rowstart[wid + 1]);
    float acc[8];
    #pragma unroll
    for (int v = 0; v < 8; ++v) acc[v] = -INFINITY;
    const unsigned short* sb = as + 512 + (size_t)lane * 8;
    int nedge = e1 - e0;
    for (int base = 0; base < nedge; base += 64) {
        int rem = nedge - base;
        int myj = csr[(lane < rem) ? (e0 + base + lane) : e0];
        int cnt = rem < 64 ? rem : 64;
        int cp = (cnt + 3) & ~3;
        for (int q = 0; q < cp; q += 4) {
            int j0 = __shfl(myj, q + 0), j1 = __shfl(myj, q + 1);
            int j2 = __shfl(myj, q + 2), j3 = __shfl(myj, q + 3);
            uint4 v0 = *(const uint4*)(sb + (size_t)j0 * 1024);
            uint4 v1 = *(const uint4*)(sb + (size_t)j1 * 1024);
            uint4 v2 = *(const uint4*)(sb + (size_t)j2 * 1024);
            uint4 v3 = *(const uint4*)(sb + (size_t)j3 * 1024);
            fmax2(acc[0], acc[1], v0.x); fmax2(acc[2], acc[3], v0.y);
            fmax2(acc[4], acc[5], v0.z); fmax2(acc[6], acc[7], v0.w);
            fmax2(acc[0], acc[1], v1.x); fmax2(acc[2], acc[3], v1.y);
            fmax2(acc[4], acc[5], v1.z); fmax2(acc[6], acc[7], v1.w);
            fmax2(acc[0], acc[1], v2.x); fmax2(acc[2], acc[3], v2.y);
            fmax2(acc[4], acc[5], v2.z); fmax2(acc[6], acc[7], v2.w);
            fmax2(acc[0], acc[1], v3.x); fmax2(acc[2], acc[3], v3.y);
            fmax2(acc[4], acc[5], v3.z); fmax2(acc[6], acc[7], v3.w);
        }
    }
    uint4 av = *(const uint4*)(as + (size_t)wid * 1024 + lane * 8);
    uint4 o;
    o.x = addrelu2(av.x, acc[0], acc[1]);
    o.y = addrelu2(av.y, acc[2], acc[3]);
    o.z = addrelu2(av.z, acc[4], acc[5]);
    o.w = addrelu2(av.w, acc[6], acc[7]);
    *(uint4*)(xout + (size_t)wid * 512 + lane * 8) = o;
}

// ---------------- N-loop MFMA GEMM: A staged in LDS ONCE, loop over N-tiles ----------------
// K compile-time (<=128), N = NT*128. One block per 128-row stripe; B is tiny (L2-hot).

template<int K, int NT>
__global__ __launch_bounds__(256) void mfma_gemm_nloop_kernel(
    const unsigned short* __restrict__ A, const unsigned short* __restrict__ Bt,
    const float* __restrict__ bias, int bias_n,
    unsigned short* __restrict__ C, int M) {
    constexpr int KC = K / 32;       // k-chunks
    constexpr int N = NT * 128;
    __shared__ __align__(16) unsigned short Asl[KC][128 * 40];
    __shared__ __align__(16) unsigned short Bsl[128 * 40];
    int tid = threadIdx.x;
    int mbase = blockIdx.x * 128;
    int wave = tid >> 6, lane = tid & 63;
    int wm = (wave >> 1) * 64, wn = (wave & 1) * 64;
    int quad = lane >> 4, l16 = lane & 15;

    // stage ALL of A once: KC*512 chunks of 16B
    #pragma unroll
    for (int c = tid; c < KC * 512; c += 256) {
        int kc = c >> 9, rem = c & 511;
        int r = rem >> 2, kk = (rem & 3) * 8;
        uint4 va = make_uint4(0u, 0u, 0u, 0u);
        int gr = mbase + r;
        if (gr < M) va = *(const uint4*)&A[(size_t)gr * K + kc * 32 + kk];
        *(uint4*)&Asl[kc][r * 40 + kk] = va;
    }

    for (int nt = 0; nt < NT; ++nt) {
        int nbase = nt * 128;
        f32x4 acc[4][4] = {};
        for (int kc = 0; kc < KC; ++kc) {
            __syncthreads();   // protect Bsl reuse (and A on first iter)
            #pragma unroll
            for (int h = 0; h < 2; ++h) {
                int c = tid + h * 256;
                int r = c >> 2, kk = (c & 3) * 8;
                uint4 vb = *(const uint4*)&Bt[(size_t)(nbase + r) * K + kc * 32 + kk];
                *(uint4*)&Bsl[r * 40 + kk] = vb;
            }
            __syncthreads();
            bf16x8 af[4], bfr[4];
            #pragma unroll
            for (int tt = 0; tt < 4; ++tt) {
                af[tt]  = *(const bf16x8*)&Asl[kc][(wm + tt * 16 + l16) * 40 + quad * 8];
                bfr[tt] = *(const bf16x8*)&Bsl[(wn + tt * 16 + l16) * 40 + quad * 8];
            }
            #pragma unroll
            for (int mt = 0; mt < 4; ++mt)
                #pragma unroll
                for (int ntt = 0; ntt < 4; ++ntt)
                    acc[mt][ntt] = __builtin_amdgcn_mfma_f32_16x16x32_bf16(
                        af[mt], bfr[ntt], acc[mt][ntt], 0, 0, 0);
        }
        #pragma unroll
        for (int mt = 0; mt < 4; ++mt) {
            #pragma unroll
            for (int r = 0; r < 4; ++r) {
                int row = mbase + wm + mt * 16 + quad * 4 + r;
                if (row >= M) continue;
                #pragma unroll
                for (int ntt = 0; ntt < 4; ++ntt) {
                    int col = nbase + wn + ntt * 16 + l16;
                    float v = acc[mt][ntt][r];
                    if (col < bias_n) v += bias[col];
                    C[(size_t)row * N + col] = f2bf(v);
                }
            }
        }
    }
}

// ---------------- fused last stage: out += relu(x3@W4 + b4) @ W5 ----------------

__global__ __launch_bounds__(256) void mfma_gemm_w5_kernel(
    const unsigned short* __restrict__ A, const unsigned short* __restrict__ Bt,
    const float* __restrict__ b4, const float* __restrict__ W5,
    float* __restrict__ out, int M, int K) {
    __shared__ __align__(16) unsigned short Asl[128 * 40];
    __shared__ __align__(16) unsigned short Bsl[128 * 40];
    int tid = threadIdx.x;
    int mbase = blockIdx.y * 128, nbase = blockIdx.x * 128;
    int wave = tid >> 6, lane = tid & 63;
    int wm = (wave >> 1) * 64, wn = (wave & 1) * 64;
    int quad = lane >> 4, l16 = lane & 15;
    f32x4 acc[4][4] = {};
    for (int kb = 0; kb < K; kb += 32) {
        #pragma unroll
        for (int h = 0; h < 2; ++h) {
            int c = tid + h * 256;
            int r = c >> 2, kk = (c & 3) * 8;
            uint4 va = make_uint4(0u, 0u, 0u, 0u);
            int gr = mbase + r;
            if (gr < M) va = *(const uint4*)&A[(size_t)gr * K + kb + kk];
            *(uint4*)&Asl[r * 40 + kk] = va;
            uint4 vb = *(const uint4*)&Bt[(size_t)(nbase + r) * K + kb + kk];
            *(uint4*)&Bsl[r * 40 + kk] = vb;
        }
        __syncthreads();
        bf16x8 af[4], bfr[4];
        #pragma unroll
        for (int tt = 0; tt < 4; ++tt) {
            af[tt]  = *(const bf16x8*)&Asl[(wm + tt * 16 + l16) * 40 + quad * 8];
            bfr[tt] = *(const bf16x8*)&Bsl[(wn + tt * 16 + l16) * 40 + quad * 8];
        }
        #pragma unroll
        for (int mt = 0; mt < 4; ++mt)
            #pragma unroll
            for (int nt = 0; nt < 4; ++nt)
                acc[mt][nt] = __builtin_amdgcn_mfma_f32_16x16x32_bf16(
                    af[mt], bfr[nt], acc[mt][nt], 0, 0, 0);
        __syncthreads();
    }
    float w5r[4][3], b4v[4];
    #pragma unroll
    for (int nt = 0; nt < 4; ++nt) {
        int col = nbase + wn + nt * 16 + l16;
        b4v[nt] = b4[col];
        w5r[nt][0] = W5[col * 3 + 0];
        w5r[nt][1] = W5[col * 3 + 1];
        w5r[nt][2] = W5[col * 3 + 2];
    }
    #pragma unroll
    for (int mt = 0; mt < 4; ++mt) {
        #pragma unroll
        for (int r = 0; r < 4; ++r) {
            int row = mbase + wm + mt * 16 + quad * 4 + r;
            float p0 = 0.f, p1 = 0.f, p2 = 0.f;
            #pragma unroll
            for (int nt = 0; nt < 4; ++nt) {
                float h = fmaxf(acc[mt][nt][r] + b4v[nt], 0.f);
                p0 += h * w5r[nt][0];
                p1 += h * w5r[nt][1];
                p2 += h * w5r[nt][2];
            }
            #pragma unroll
            for (int m = 8; m; m >>= 1) {
                p0 += __shfl_xor(p0, m);
                p1 += __shfl_xor(p1, m);
                p2 += __shfl_xor(p2, m);
            }
            if (l16 == 0 && row < M) {
                atomicAdd(&out[row * 3 + 0], p0);
                atomicAdd(&out[row * 3 + 1], p1);
                atomicAdd(&out[row * 3 + 2], p2);
            }
        }
    }
}

__global__ void fallback_copy_kernel(const float* __restrict__ x, float* __restrict__ out) {
    int t = blockIdx.x * blockDim.x + threadIdx.x;
    if (t < NN * 3) out[t] = x[t];
}

// ---------------- launcher ----------------

extern "C" void kernel_launch(void* const* d_in, const int* in_sizes, int n_in,
                              void* d_out, int out_size, void* d_ws, size_t ws_size,
                              hipStream_t stream) {
    const float* x  = (const float*)d_in[0];
    const int*   ei = (const int*)d_in[1];
    const float* W1 = (const float*)d_in[2];
    const float* b1 = (const float*)d_in[3];
    const float* W2 = (const float*)d_in[4];
    const float* b2 = (const float*)d_in[5];
    const float* W3 = (const float*)d_in[6];
    const float* b3 = (const float*)d_in[7];
    const float* W4 = (const float*)d_in[8];
    const float* b4 = (const float*)d_in[9];
    const float* W5 = (const float*)d_in[10];
    const float* b5 = (const float*)d_in[11];
    float* out = (float*)d_out;

    char* p = (char*)d_ws;
    auto alloc = [&](size_t bytes) -> void* {
        void* r = (void*)p;
        p += (bytes + 255) & ~(size_t)255;
        return r;
    };
    int* deg      = (int*)alloc((size_t)NN * 4);
    int* rowstart = (int*)alloc((size_t)(NN + 1) * 4);
    int* cursor   = (int*)alloc((size_t)NN * 4);
    int* csr      = (int*)alloc((size_t)NE * 4);
    unsigned short* Bt2 = (unsigned short*)alloc(256 * 64 * 2);
    unsigned short* Bt3 = (unsigned short*)alloc(1024 * 128 * 2);
    unsigned short* W4t = (unsigned short*)alloc(256 * 512 * 2);
    unsigned short* x1 = (unsigned short*)alloc((size_t)NN * 64 * 2);
    unsigned short* x2 = (unsigned short*)alloc((size_t)NN * 128 * 2);
    unsigned short* x3 = (unsigned short*)alloc((size_t)NN * 512 * 2);
    unsigned short* as_slab = (unsigned short*)alloc((size_t)NN * 1024 * 2);  // as1/as2/as3
    size_t need = (size_t)(p - (char*)d_ws);
    if (ws_size < need) {
        fallback_copy_kernel<<<(NN * 3 + 255) / 256, 256, 0, stream>>>(x, out);
        return;
    }

    const int* src = ei;        // edge_index[0]
    const int* dst = ei + NE;   // edge_index[1]

    // merged setup (one dispatch)
    constexpr int SETUP_T = NN * 128 + NN * 3 + NN + NN + 8192 + 65536 + 131072;
    setup_kernel<<<(SETUP_T + 255) / 256, 256, 0, stream>>>(
        x, W1, b1, b5, W2, W3, W4, as_slab, out, deg, cursor, Bt2, Bt3, W4t);

    // CSR by dst (graph static across all 3 convs)
    hist_kernel<<<(NE + 255) / 256, 256, 0, stream>>>(dst, deg);
    scan_kernel<<<1, 1024, 0, stream>>>(deg, rowstart);
    scatter_kernel<<<(NE + 255) / 256, 256, 0, stream>>>(src, dst, rowstart, cursor, csr);

    // conv1: x1 = relu(a1 + max_j s1[j])
    edge_fused_conv1_kernel<<<12500, 256, 0, stream>>>(as_slab, rowstart, csr, x1);

    // conv2: as2 = x1 @ [Wtb2|Wb2] (+b2 on a-half); x2 = relu(a2 + max s2)
    mfma_gemm_nloop_kernel<64, 2><<<391, 256, 0, stream>>>(
        x1, Bt2, b2, 128, as_slab, NN);
    edge_fused128_kernel<<<12500, 256, 0, stream>>>(as_slab, rowstart, csr, x2);

    // conv3: as3 = x2 @ [Wtb3|Wb3] (+b3 on a-half); x3 = relu(a3 + max s3)
    mfma_gemm_nloop_kernel<128, 8><<<391, 256, 0, stream>>>(
        x2, Bt3, b3, 512, as_slab, NN);
    edge_fused512_kernel<<<12500, 256, 0, stream>>>(as_slab, rowstart, csr, x3);

    // out += relu(x3@W4 + b4) @ W5   (fused, no h4 materialization)
    mfma_gemm_w5_kernel<<<dim3(2, 391), 256, 0, stream>>>(
        x3, W4t, b4, W5, out, NN, 512);
}

// Round 10
// 614.319 us; speedup vs baseline: 1.4100x; 1.0068x over previous
//
#include <hip/hip_runtime.h>

static constexpr int NN = 50000;
static constexpr int NE = 1000000;

typedef short bf16x8 __attribute__((ext_vector_type(8)));
typedef float f32x4 __attribute__((ext_vector_type(4)));

__device__ inline float bf2f_raw(unsigned short u) {
    return __uint_as_float(((unsigned int)u) << 16);
}
__device__ inline unsigned short f2bf(float f) {
    unsigned int u = __float_as_uint(f);
    u += 0x7fffu + ((u >> 16) & 1u);
    return (unsigned short)(u >> 16);
}
__device__ inline void fmax2(float& a0, float& a1, unsigned int v) {
    a0 = fmaxf(a0, bf2f_raw((unsigned short)(v & 0xffffu)));
    a1 = fmaxf(a1, bf2f_raw((unsigned short)(v >> 16)));
}
__device__ inline unsigned int pack2(float f0, float f1) {
    return (unsigned int)f2bf(f0) | ((unsigned int)f2bf(f1) << 16);
}
__device__ inline unsigned int addrelu2(unsigned int a, float t0, float t1) {
    float f0 = fmaxf(bf2f_raw((unsigned short)(a & 0xffffu)) + t0, 0.f);
    float f1 = fmaxf(bf2f_raw((unsigned short)(a >> 16)) + t1, 0.f);
    return pack2(f0, f1);
}

// ---------------- merged setup: conv1_as + out-init + deg-zero + cursor-zero + weight prep --------

__global__ void setup_kernel(const float* __restrict__ x, const float* __restrict__ W1,
                             const float* __restrict__ b1, const float* __restrict__ b5,
                             const float* __restrict__ W2, const float* __restrict__ W3,
                             const float* __restrict__ W4,
                             unsigned short* __restrict__ as1, float* __restrict__ out,
                             int* __restrict__ deg, int* __restrict__ cursor,
                             unsigned short* __restrict__ Bt2,
                             unsigned short* __restrict__ Bt3,
                             unsigned short* __restrict__ W4t) {
    int t = blockIdx.x * blockDim.x + threadIdx.x;
    if (t < NN * 128) {
        // conv1: as1[i] = [a1(64) | s1(64)],  a = x@(Wt-Wb)+b1, s = x@Wb  (W1 is [6][64])
        int i = t >> 7, c = t & 127;
        float x0 = x[i * 3 + 0], x1 = x[i * 3 + 1], x2 = x[i * 3 + 2];
        float v;
        if (c < 64) {
            v = x0 * (W1[c] - W1[192 + c]) + x1 * (W1[64 + c] - W1[256 + c]) +
                x2 * (W1[128 + c] - W1[320 + c]) + b1[c];
        } else {
            int cs = c - 64;
            v = x0 * W1[192 + cs] + x1 * W1[256 + cs] + x2 * W1[320 + cs];
        }
        as1[t] = f2bf(v);
        return;
    }
    t -= NN * 128;
    if (t < NN * 3) { out[t] = x[t] + b5[t % 3]; return; }
    t -= NN * 3;
    if (t < NN) { deg[t] = 0; return; }
    t -= NN;
    if (t < NN) { cursor[t] = 0; return; }
    t -= NN;
    if (t < 8192) {  // W2 split (64x128)
        int k = t / 128, c = t % 128;
        float wt = W2[k * 128 + c];
        float wb = W2[(64 + k) * 128 + c];
        Bt2[c * 64 + k] = f2bf(wt - wb);
        Bt2[(128 + c) * 64 + k] = f2bf(wb);
        return;
    }
    t -= 8192;
    if (t < 65536) {  // W3 split (128x512)
        int k = t / 512, c = t % 512;
        float wt = W3[k * 512 + c];
        float wb = W3[(128 + k) * 512 + c];
        Bt3[c * 128 + k] = f2bf(wt - wb);
        Bt3[(512 + c) * 128 + k] = f2bf(wb);
        return;
    }
    t -= 65536;
    if (t < 131072) {  // W4 transpose (512x256)
        int k = t / 256, n = t % 256;
        W4t[n * 512 + k] = f2bf(W4[k * 256 + n]);
    }
}

// ---------------- CSR build ----------------

__global__ void hist_kernel(const int* __restrict__ dst, int* __restrict__ deg) {
    int e = blockIdx.x * blockDim.x + threadIdx.x;
    if (e < NE) atomicAdd(&deg[dst[e]], 1);
}

// single-block scan, register-resident
__global__ __launch_bounds__(1024) void scan_kernel(const int* __restrict__ deg,
                                                    int* __restrict__ rowstart) {
    __shared__ int wave_sums[16];
    constexpr int CH = (NN + 1023) / 1024;  // 49
    int tid = threadIdx.x;
    int lane = tid & 63;
    int wave = tid >> 6;
    int base = tid * CH;
    int vals[CH];
    int sum = 0;
    #pragma unroll
    for (int i = 0; i < CH; ++i) {
        int idx = base + i;
        vals[i] = (idx < NN) ? deg[idx] : 0;
        sum += vals[i];
    }
    int x = sum;
    #pragma unroll
    for (int off = 1; off < 64; off <<= 1) {
        int y = __shfl_up(x, off);
        if (lane >= off) x += y;
    }
    if (lane == 63) wave_sums[wave] = x;
    __syncthreads();
    if (wave == 0 && lane < 16) {
        int s = wave_sums[lane];
        #pragma unroll
        for (int off = 1; off < 16; off <<= 1) {
            int y = __shfl_up(s, off);
            if (lane >= off) s += y;
        }
        wave_sums[lane] = s;
    }
    __syncthreads();
    int run = (wave ? wave_sums[wave - 1] : 0) + x - sum;
    #pragma unroll
    for (int i = 0; i < CH; ++i) {
        int idx = base + i;
        if (idx < NN) rowstart[idx] = run;
        run += vals[i];
    }
    if (tid == 1023) rowstart[NN] = run;
}

__global__ void scatter_kernel(const int* __restrict__ src, const int* __restrict__ dst,
                               const int* __restrict__ rowstart, int* __restrict__ cursor,
                               int* __restrict__ csr) {
    int e = blockIdx.x * blockDim.x + threadIdx.x;
    if (e < NE) {
        int d = dst[e];
        int pos = atomicAdd(&cursor[d], 1);
        csr[rowstart[d] + pos] = src[e];
    }
}

// ---------------- conv1 fused edge-max + epilogue (C=64, as rows [a(64)|s(64)]) ----------------

__global__ __launch_bounds__(256) void edge_fused_conv1_kernel(
    const unsigned short* __restrict__ as, const int* __restrict__ rowstart,
    const int* __restrict__ csr, unsigned short* __restrict__ x1) {
    int wid = (blockIdx.x * 256 + threadIdx.x) >> 6;
    int lane = threadIdx.x & 63;
    if (wid >= NN) return;
    int e0 = __builtin_amdgcn_readfirstlane(rowstart[wid]);
    int e1 = __builtin_amdgcn_readfirstlane(rowstart[wid + 1]);
    int h = lane >> 5, c0 = (lane & 31) * 2;
    float t0 = -INFINITY, t1 = -INFINITY;
    const unsigned short* sb = as + 64 + c0;
    int nedge = e1 - e0;
    for (int base = 0; base < nedge; base += 64) {
        int rem = nedge - base;
        int myj = csr[(lane < rem) ? (e0 + base + lane) : e0];
        int cnt = rem < 64 ? rem : 64;
        int cp = (cnt + 7) & ~7;
        for (int q = 0; q < cp; q += 8) {
            int j0 = __shfl(myj, q + 0 + h);
            int j1 = __shfl(myj, q + 2 + h);
            int j2 = __shfl(myj, q + 4 + h);
            int j3 = __shfl(myj, q + 6 + h);
            unsigned int v0 = *(const unsigned int*)(sb + (size_t)j0 * 128);
            unsigned int v1 = *(const unsigned int*)(sb + (size_t)j1 * 128);
            unsigned int v2 = *(const unsigned int*)(sb + (size_t)j2 * 128);
            unsigned int v3 = *(const unsigned int*)(sb + (size_t)j3 * 128);
            fmax2(t0, t1, v0);
            fmax2(t0, t1, v1);
            fmax2(t0, t1, v2);
            fmax2(t0, t1, v3);
        }
    }
    t0 = fmaxf(t0, __shfl_xor(t0, 32));
    t1 = fmaxf(t1, __shfl_xor(t1, 32));
    if (h == 0) {
        unsigned int av = *(const unsigned int*)(as + (size_t)wid * 128 + c0);
        *(unsigned int*)(x1 + (size_t)wid * 64 + c0) = addrelu2(av, t0, t1);
    }
}

// ---------------- fused edge-max + epilogue, C=128 (as rows [a(128)|s(128)]) ----------------

__global__ __launch_bounds__(256) void edge_fused128_kernel(
    const unsigned short* __restrict__ as, const int* __restrict__ rowstart,
    const int* __restrict__ csr, unsigned short* __restrict__ xout) {
    int wid = (blockIdx.x * 256 + threadIdx.x) >> 6;
    int lane = threadIdx.x & 63;
    if (wid >= NN) return;
    int e0 = __builtin_amdgcn_readfirstlane(rowstart[wid]);
    int e1 = __builtin_amdgcn_readfirstlane(rowstart[wid + 1]);
    float t0 = -INFINITY, t1 = -INFINITY;
    const unsigned short* sb = as + 128 + (size_t)lane * 2;
    int nedge = e1 - e0;
    for (int base = 0; base < nedge; base += 64) {
        int rem = nedge - base;
        int myj = csr[(lane < rem) ? (e0 + base + lane) : e0];
        int cnt = rem < 64 ? rem : 64;
        int cp = (cnt + 7) & ~7;
        for (int q = 0; q < cp; q += 8) {
            int j0 = __shfl(myj, q + 0), j1 = __shfl(myj, q + 1);
            int j2 = __shfl(myj, q + 2), j3 = __shfl(myj, q + 3);
            int j4 = __shfl(myj, q + 4), j5 = __shfl(myj, q + 5);
            int j6 = __shfl(myj, q + 6), j7 = __shfl(myj, q + 7);
            unsigned int v0 = *(const unsigned int*)(sb + (size_t)j0 * 256);
            unsigned int v1 = *(const unsigned int*)(sb + (size_t)j1 * 256);
            unsigned int v2 = *(const unsigned int*)(sb + (size_t)j2 * 256);
            unsigned int v3 = *(const unsigned int*)(sb + (size_t)j3 * 256);
            unsigned int v4 = *(const unsigned int*)(sb + (size_t)j4 * 256);
            unsigned int v5 = *(const unsigned int*)(sb + (size_t)j5 * 256);
            unsigned int v6 = *(const unsigned int*)(sb + (size_t)j6 * 256);
            unsigned int v7 = *(const unsigned int*)(sb + (size_t)j7 * 256);
            fmax2(t0, t1, v0); fmax2(t0, t1, v1);
            fmax2(t0, t1, v2); fmax2(t0, t1, v3);
            fmax2(t0, t1, v4); fmax2(t0, t1, v5);
            fmax2(t0, t1, v6); fmax2(t0, t1, v7);
        }
    }
    unsigned int av = *(const unsigned int*)(as + (size_t)wid * 256 + lane * 2);
    *(unsigned int*)(xout + (size_t)wid * 128 + lane * 2) = addrelu2(av, t0, t1);
}

// ---------------- fused edge-max + epilogue, C=512 (as rows [a(512)|s(512)]) ----------------

__global__ __launch_bounds__(256) void edge_fused512_kernel(
    const unsigned short* __restrict__ as, const int* __restrict__ rowstart,
    const int* __restrict__ csr, unsigned short* __restrict__ xout) {
    int wid = (blockIdx.x * 256 + threadIdx.x) >> 6;
    int lane = threadIdx.x & 63;
    if (wid >= NN) return;
    int e0 = __builtin_amdgcn_readfirstlane(rowstart[wid]);
    int e1 = __builtin_amdgcn_readfirstlane(rowstart[wid + 1]);
    float acc[8];
    #pragma unroll
    for (int v = 0; v < 8; ++v) acc[v] = -INFINITY;
    const unsigned short* sb = as + 512 + (size_t)lane * 8;
    int nedge = e1 - e0;
    for (int base = 0; base < nedge; base += 64) {
        int rem = nedge - base;
        int myj = csr[(lane < rem) ? (e0 + base + lane) : e0];
        int cnt = rem < 64 ? rem : 64;
        int cp = (cnt + 3) & ~3;
        for (int q = 0; q < cp; q += 4) {
            int j0 = __shfl(myj, q + 0), j1 = __shfl(myj, q + 1);
            int j2 = __shfl(myj, q + 2), j3 = __shfl(myj, q + 3);
            uint4 v0 = *(const uint4*)(sb + (size_t)j0 * 1024);
            uint4 v1 = *(const uint4*)(sb + (size_t)j1 * 1024);
            uint4 v2 = *(const uint4*)(sb + (size_t)j2 * 1024);
            uint4 v3 = *(const uint4*)(sb + (size_t)j3 * 1024);
            fmax2(acc[0], acc[1], v0.x); fmax2(acc[2], acc[3], v0.y);
            fmax2(acc[4], acc[5], v0.z); fmax2(acc[6], acc[7], v0.w);
            fmax2(acc[0], acc[1], v1.x); fmax2(acc[2], acc[3], v1.y);
            fmax2(acc[4], acc[5], v1.z); fmax2(acc[6], acc[7], v1.w);
            fmax2(acc[0], acc[1], v2.x); fmax2(acc[2], acc[3], v2.y);
            fmax2(acc[4], acc[5], v2.z); fmax2(acc[6], acc[7], v2.w);
            fmax2(acc[0], acc[1], v3.x); fmax2(acc[2], acc[3], v3.y);
            fmax2(acc[4], acc[5], v3.z); fmax2(acc[6], acc[7], v3.w);
        }
    }
    uint4 av = *(const uint4*)(as + (size_t)wid * 1024 + lane * 8);
    uint4 o;
    o.x = addrelu2(av.x, acc[0], acc[1]);
    o.y = addrelu2(av.y, acc[2], acc[3]);
    o.z = addrelu2(av.z, acc[4], acc[5]);
    o.w = addrelu2(av.w, acc[6], acc[7]);
    *(uint4*)(xout + (size_t)wid * 512 + lane * 8) = o;
}

// ---------------- N-loop MFMA GEMM: A staged in LDS ONCE, loop over N-tiles ----------------

template<int K, int NT>
__global__ __launch_bounds__(256) void mfma_gemm_nloop_kernel(
    const unsigned short* __restrict__ A, const unsigned short* __restrict__ Bt,
    const float* __restrict__ bias, int bias_n,
    unsigned short* __restrict__ C, int M) {
    constexpr int KC = K / 32;       // k-chunks
    constexpr int N = NT * 128;
    __shared__ __align__(16) unsigned short Asl[KC][128 * 40];
    __shared__ __align__(16) unsigned short Bsl[128 * 40];
    int tid = threadIdx.x;
    int mbase = blockIdx.x * 128;
    int wave = tid >> 6, lane = tid & 63;
    int wm = (wave >> 1) * 64, wn = (wave & 1) * 64;
    int quad = lane >> 4, l16 = lane & 15;

    // stage ALL of A once: KC*512 chunks of 16B
    #pragma unroll
    for (int c = tid; c < KC * 512; c += 256) {
        int kc = c >> 9, rem = c & 511;
        int r = rem >> 2, kk = (rem & 3) * 8;
        uint4 va = make_uint4(0u, 0u, 0u, 0u);
        int gr = mbase + r;
        if (gr < M) va = *(const uint4*)&A[(size_t)gr * K + kc * 32 + kk];
        *(uint4*)&Asl[kc][r * 40 + kk] = va;
    }

    for (int nt = 0; nt < NT; ++nt) {
        int nbase = nt * 128;
        f32x4 acc[4][4] = {};
        for (int kc = 0; kc < KC; ++kc) {
            __syncthreads();
            #pragma unroll
            for (int h = 0; h < 2; ++h) {
                int c = tid + h * 256;
                int r = c >> 2, kk = (c & 3) * 8;
                uint4 vb = *(const uint4*)&Bt[(size_t)(nbase + r) * K + kc * 32 + kk];
                *(uint4*)&Bsl[r * 40 + kk] = vb;
            }
            __syncthreads();
            bf16x8 af[4], bfr[4];
            #pragma unroll
            for (int tt = 0; tt < 4; ++tt) {
                af[tt]  = *(const bf16x8*)&Asl[kc][(wm + tt * 16 + l16) * 40 + quad * 8];
                bfr[tt] = *(const bf16x8*)&Bsl[(wn + tt * 16 + l16) * 40 + quad * 8];
            }
            #pragma unroll
            for (int mt = 0; mt < 4; ++mt)
                #pragma unroll
                for (int ntt = 0; ntt < 4; ++ntt)
                    acc[mt][ntt] = __builtin_amdgcn_mfma_f32_16x16x32_bf16(
                        af[mt], bfr[ntt], acc[mt][ntt], 0, 0, 0);
        }
        #pragma unroll
        for (int mt = 0; mt < 4; ++mt) {
            #pragma unroll
            for (int r = 0; r < 4; ++r) {
                int row = mbase + wm + mt * 16 + quad * 4 + r;
                if (row >= M) continue;
                #pragma unroll
                for (int ntt = 0; ntt < 4; ++ntt) {
                    int col = nbase + wn + ntt * 16 + l16;
                    float v = acc[mt][ntt][r];
                    if (col < bias_n) v += bias[col];
                    C[(size_t)row * N + col] = f2bf(v);
                }
            }
        }
    }
}

// ---------------- fused last stage: out += relu(x3@W4 + b4) @ W5 ----------------
// One block per 128-row stripe; nt-loop outside K so the A-stripe re-read (nt=1)
// hits this block's own XCD L2 (128 KB, resident) — no XCD-mapping assumption.

__global__ __launch_bounds__(256) void mfma_gemm_w5_kernel(
    const unsigned short* __restrict__ A, const unsigned short* __restrict__ Bt,
    const float* __restrict__ b4, const float* __restrict__ W5,
    float* __restrict__ out, int M, int K) {
    __shared__ __align__(16) unsigned short Asl[128 * 40];
    __shared__ __align__(16) unsigned short Bsl[128 * 40];
    int tid = threadIdx.x;
    int mbase = blockIdx.x * 128;
    int wave = tid >> 6, lane = tid & 63;
    int wm = (wave >> 1) * 64, wn = (wave & 1) * 64;
    int quad = lane >> 4, l16 = lane & 15;
    for (int nt = 0; nt < 2; ++nt) {
        int nbase = nt * 128;
        f32x4 acc[4][4] = {};
        for (int kb = 0; kb < K; kb += 32) {
            __syncthreads();
            #pragma unroll
            for (int h = 0; h < 2; ++h) {
                int c = tid + h * 256;
                int r = c >> 2, kk = (c & 3) * 8;
                uint4 va = make_uint4(0u, 0u, 0u, 0u);
                int gr = mbase + r;
                if (gr < M) va = *(const uint4*)&A[(size_t)gr * K + kb + kk];
                *(uint4*)&Asl[r * 40 + kk] = va;
                uint4 vb = *(const uint4*)&Bt[(size_t)(nbase + r) * K + kb + kk];
                *(uint4*)&Bsl[r * 40 + kk] = vb;
            }
            __syncthreads();
            bf16x8 af[4], bfr[4];
            #pragma unroll
            for (int tt = 0; tt < 4; ++tt) {
                af[tt]  = *(const bf16x8*)&Asl[(wm + tt * 16 + l16) * 40 + quad * 8];
                bfr[tt] = *(const bf16x8*)&Bsl[(wn + tt * 16 + l16) * 40 + quad * 8];
            }
            #pragma unroll
            for (int mt = 0; mt < 4; ++mt)
                #pragma unroll
                for (int ntt = 0; ntt < 4; ++ntt)
                    acc[mt][ntt] = __builtin_amdgcn_mfma_f32_16x16x32_bf16(
                        af[mt], bfr[ntt], acc[mt][ntt], 0, 0, 0);
        }
        float w5r[4][3], b4v[4];
        #pragma unroll
        for (int ntt = 0; ntt < 4; ++ntt) {
            int col = nbase + wn + ntt * 16 + l16;
            b4v[ntt] = b4[col];
            w5r[ntt][0] = W5[col * 3 + 0];
            w5r[ntt][1] = W5[col * 3 + 1];
            w5r[ntt][2] = W5[col * 3 + 2];
        }
        #pragma unroll
        for (int mt = 0; mt < 4; ++mt) {
            #pragma unroll
            for (int r = 0; r < 4; ++r) {
                int row = mbase + wm + mt * 16 + quad * 4 + r;
                float p0 = 0.f, p1 = 0.f, p2 = 0.f;
                #pragma unroll
                for (int ntt = 0; ntt < 4; ++ntt) {
                    float h = fmaxf(acc[mt][ntt][r] + b4v[ntt], 0.f);
                    p0 += h * w5r[ntt][0];
                    p1 += h * w5r[ntt][1];
                    p2 += h * w5r[ntt][2];
                }
                #pragma unroll
                for (int m = 8; m; m >>= 1) {
                    p0 += __shfl_xor(p0, m);
                    p1 += __shfl_xor(p1, m);
                    p2 += __shfl_xor(p2, m);
                }
                if (l16 == 0 && row < M) {
                    atomicAdd(&out[row * 3 + 0], p0);
                    atomicAdd(&out[row * 3 + 1], p1);
                    atomicAdd(&out[row * 3 + 2], p2);
                }
            }
        }
    }
}

__global__ void fallback_copy_kernel(const float* __restrict__ x, float* __restrict__ out) {
    int t = blockIdx.x * blockDim.x + threadIdx.x;
    if (t < NN * 3) out[t] = x[t];
}

// ---------------- launcher ----------------

extern "C" void kernel_launch(void* const* d_in, const int* in_sizes, int n_in,
                              void* d_out, int out_size, void* d_ws, size_t ws_size,
                              hipStream_t stream) {
    const float* x  = (const float*)d_in[0];
    const int*   ei = (const int*)d_in[1];
    const float* W1 = (const float*)d_in[2];
    const float* b1 = (const float*)d_in[3];
    const float* W2 = (const float*)d_in[4];
    const float* b2 = (const float*)d_in[5];
    const float* W3 = (const float*)d_in[6];
    const float* b3 = (const float*)d_in[7];
    const float* W4 = (const float*)d_in[8];
    const float* b4 = (const float*)d_in[9];
    const float* W5 = (const float*)d_in[10];
    const float* b5 = (const float*)d_in[11];
    float* out = (float*)d_out;

    char* p = (char*)d_ws;
    auto alloc = [&](size_t bytes) -> void* {
        void* r = (void*)p;
        p += (bytes + 255) & ~(size_t)255;
        return r;
    };
    int* deg      = (int*)alloc((size_t)NN * 4);
    int* rowstart = (int*)alloc((size_t)(NN + 1) * 4);
    int* cursor   = (int*)alloc((size_t)NN * 4);
    int* csr      = (int*)alloc((size_t)NE * 4);
    unsigned short* Bt2 = (unsigned short*)alloc(256 * 64 * 2);
    unsigned short* Bt3 = (unsigned short*)alloc(1024 * 128 * 2);
    unsigned short* W4t = (unsigned short*)alloc(256 * 512 * 2);
    unsigned short* x1 = (unsigned short*)alloc((size_t)NN * 64 * 2);
    unsigned short* x2 = (unsigned short*)alloc((size_t)NN * 128 * 2);
    unsigned short* x3 = (unsigned short*)alloc((size_t)NN * 512 * 2);
    unsigned short* as_slab = (unsigned short*)alloc((size_t)NN * 1024 * 2);  // as1/as2/as3
    size_t need = (size_t)(p - (char*)d_ws);
    if (ws_size < need) {
        fallback_copy_kernel<<<(NN * 3 + 255) / 256, 256, 0, stream>>>(x, out);
        return;
    }

    const int* src = ei;        // edge_index[0]
    const int* dst = ei + NE;   // edge_index[1]

    // merged setup (one dispatch)
    constexpr int SETUP_T = NN * 128 + NN * 3 + NN + NN + 8192 + 65536 + 131072;
    setup_kernel<<<(SETUP_T + 255) / 256, 256, 0, stream>>>(
        x, W1, b1, b5, W2, W3, W4, as_slab, out, deg, cursor, Bt2, Bt3, W4t);

    // CSR by dst (graph static across all 3 convs)
    hist_kernel<<<(NE + 255) / 256, 256, 0, stream>>>(dst, deg);
    scan_kernel<<<1, 1024, 0, stream>>>(deg, rowstart);
    scatter_kernel<<<(NE + 255) / 256, 256, 0, stream>>>(src, dst, rowstart, cursor, csr);

    // conv1: x1 = relu(a1 + max_j s1[j])
    edge_fused_conv1_kernel<<<12500, 256, 0, stream>>>(as_slab, rowstart, csr, x1);

    // conv2: as2 = x1 @ [Wtb2|Wb2] (+b2 on a-half); x2 = relu(a2 + max s2)
    mfma_gemm_nloop_kernel<64, 2><<<391, 256, 0, stream>>>(
        x1, Bt2, b2, 128, as_slab, NN);
    edge_fused128_kernel<<<12500, 256, 0, stream>>>(as_slab, rowstart, csr, x2);

    // conv3: as3 = x2 @ [Wtb3|Wb3] (+b3 on a-half); x3 = relu(a3 + max s3)
    mfma_gemm_nloop_kernel<128, 8><<<391, 256, 0, stream>>>(
        x2, Bt3, b3, 512, as_slab, NN);
    edge_fused512_kernel<<<12500, 256, 0, stream>>>(as_slab, rowstart, csr, x3);

    // out += relu(x3@W4 + b4) @ W5   (fused; nt-loop per stripe so A re-read is L2-hot)
    mfma_gemm_w5_kernel<<<391, 256, 0, stream>>>(
        x3, W4t, b4, W5, out, NN, 512);
}

// Round 11
// 589.255 us; speedup vs baseline: 1.4700x; 1.0425x over previous
//
#include <hip/hip_runtime.h>

static constexpr int NN = 50000;
static constexpr int NE = 1000000;

typedef short bf16x8 __attribute__((ext_vector_type(8)));
typedef float f32x4 __attribute__((ext_vector_type(4)));

__device__ inline float bf2f_raw(unsigned short u) {
    return __uint_as_float(((unsigned int)u) << 16);
}
__device__ inline unsigned short f2bf(float f) {
    unsigned int u = __float_as_uint(f);
    u += 0x7fffu + ((u >> 16) & 1u);
    return (unsigned short)(u >> 16);
}
__device__ inline void fmax2(float& a0, float& a1, unsigned int v) {
    a0 = fmaxf(a0, bf2f_raw((unsigned short)(v & 0xffffu)));
    a1 = fmaxf(a1, bf2f_raw((unsigned short)(v >> 16)));
}
__device__ inline unsigned int pack2(float f0, float f1) {
    return (unsigned int)f2bf(f0) | ((unsigned int)f2bf(f1) << 16);
}
__device__ inline unsigned int addrelu2(unsigned int a, float t0, float t1) {
    float f0 = fmaxf(bf2f_raw((unsigned short)(a & 0xffffu)) + t0, 0.f);
    float f1 = fmaxf(bf2f_raw((unsigned short)(a >> 16)) + t1, 0.f);
    return pack2(f0, f1);
}

// ---------------- merged setup: conv1_as + out-init + deg-zero + cursor-zero + weight prep --------

__global__ void setup_kernel(const float* __restrict__ x, const float* __restrict__ W1,
                             const float* __restrict__ b1, const float* __restrict__ b5,
                             const float* __restrict__ W2, const float* __restrict__ W3,
                             const float* __restrict__ W4,
                             unsigned short* __restrict__ as1, float* __restrict__ out,
                             int* __restrict__ deg, int* __restrict__ cursor,
                             unsigned short* __restrict__ Bt2,
                             unsigned short* __restrict__ Bt3,
                             unsigned short* __restrict__ W4t) {
    int t = blockIdx.x * blockDim.x + threadIdx.x;
    if (t < NN * 128) {
        // conv1: as1[i] = [a1(64) | s1(64)],  a = x@(Wt-Wb)+b1, s = x@Wb  (W1 is [6][64])
        int i = t >> 7, c = t & 127;
        float x0 = x[i * 3 + 0], x1 = x[i * 3 + 1], x2 = x[i * 3 + 2];
        float v;
        if (c < 64) {
            v = x0 * (W1[c] - W1[192 + c]) + x1 * (W1[64 + c] - W1[256 + c]) +
                x2 * (W1[128 + c] - W1[320 + c]) + b1[c];
        } else {
            int cs = c - 64;
            v = x0 * W1[192 + cs] + x1 * W1[256 + cs] + x2 * W1[320 + cs];
        }
        as1[t] = f2bf(v);
        return;
    }
    t -= NN * 128;
    if (t < NN * 3) { out[t] = x[t] + b5[t % 3]; return; }
    t -= NN * 3;
    if (t < NN) { deg[t] = 0; return; }
    t -= NN;
    if (t < NN) { cursor[t] = 0; return; }
    t -= NN;
    if (t < 8192) {  // W2 split (64x128)
        int k = t / 128, c = t % 128;
        float wt = W2[k * 128 + c];
        float wb = W2[(64 + k) * 128 + c];
        Bt2[c * 64 + k] = f2bf(wt - wb);
        Bt2[(128 + c) * 64 + k] = f2bf(wb);
        return;
    }
    t -= 8192;
    if (t < 65536) {  // W3 split (128x512)
        int k = t / 512, c = t % 512;
        float wt = W3[k * 512 + c];
        float wb = W3[(128 + k) * 512 + c];
        Bt3[c * 128 + k] = f2bf(wt - wb);
        Bt3[(512 + c) * 128 + k] = f2bf(wb);
        return;
    }
    t -= 65536;
    if (t < 131072) {  // W4 transpose (512x256)
        int k = t / 256, n = t % 256;
        W4t[n * 512 + k] = f2bf(W4[k * 256 + n]);
    }
}

// ---------------- CSR build ----------------

__global__ void hist_kernel(const int* __restrict__ dst, int* __restrict__ deg) {
    int e = blockIdx.x * blockDim.x + threadIdx.x;
    if (e < NE) atomicAdd(&deg[dst[e]], 1);
}

// single-block scan, register-resident
__global__ __launch_bounds__(1024) void scan_kernel(const int* __restrict__ deg,
                                                    int* __restrict__ rowstart) {
    __shared__ int wave_sums[16];
    constexpr int CH = (NN + 1023) / 1024;  // 49
    int tid = threadIdx.x;
    int lane = tid & 63;
    int wave = tid >> 6;
    int base = tid * CH;
    int vals[CH];
    int sum = 0;
    #pragma unroll
    for (int i = 0; i < CH; ++i) {
        int idx = base + i;
        vals[i] = (idx < NN) ? deg[idx] : 0;
        sum += vals[i];
    }
    int x = sum;
    #pragma unroll
    for (int off = 1; off < 64; off <<= 1) {
        int y = __shfl_up(x, off);
        if (lane >= off) x += y;
    }
    if (lane == 63) wave_sums[wave] = x;
    __syncthreads();
    if (wave == 0 && lane < 16) {
        int s = wave_sums[lane];
        #pragma unroll
        for (int off = 1; off < 16; off <<= 1) {
            int y = __shfl_up(s, off);
            if (lane >= off) s += y;
        }
        wave_sums[lane] = s;
    }
    __syncthreads();
    int run = (wave ? wave_sums[wave - 1] : 0) + x - sum;
    #pragma unroll
    for (int i = 0; i < CH; ++i) {
        int idx = base + i;
        if (idx < NN) rowstart[idx] = run;
        run += vals[i];
    }
    if (tid == 1023) rowstart[NN] = run;
}

__global__ void scatter_kernel(const int* __restrict__ src, const int* __restrict__ dst,
                               const int* __restrict__ rowstart, int* __restrict__ cursor,
                               int* __restrict__ csr) {
    int e = blockIdx.x * blockDim.x + threadIdx.x;
    if (e < NE) {
        int d = dst[e];
        int pos = atomicAdd(&cursor[d], 1);
        csr[rowstart[d] + pos] = src[e];
    }
}

// ---------------- conv1 fused edge-max + epilogue (C=64, as rows [a(64)|s(64)]) ----------------

__global__ __launch_bounds__(256) void edge_fused_conv1_kernel(
    const unsigned short* __restrict__ as, const int* __restrict__ rowstart,
    const int* __restrict__ csr, unsigned short* __restrict__ x1) {
    int wid = (blockIdx.x * 256 + threadIdx.x) >> 6;
    int lane = threadIdx.x & 63;
    if (wid >= NN) return;
    int e0 = __builtin_amdgcn_readfirstlane(rowstart[wid]);
    int e1 = __builtin_amdgcn_readfirstlane(rowstart[wid + 1]);
    int h = lane >> 5, c0 = (lane & 31) * 2;
    float t0 = -INFINITY, t1 = -INFINITY;
    const unsigned short* sb = as + 64 + c0;
    int nedge = e1 - e0;
    for (int base = 0; base < nedge; base += 64) {
        int rem = nedge - base;
        int myj = csr[(lane < rem) ? (e0 + base + lane) : e0];
        int cnt = rem < 64 ? rem : 64;
        int cp = (cnt + 7) & ~7;
        for (int q = 0; q < cp; q += 8) {
            int j0 = __shfl(myj, q + 0 + h);
            int j1 = __shfl(myj, q + 2 + h);
            int j2 = __shfl(myj, q + 4 + h);
            int j3 = __shfl(myj, q + 6 + h);
            unsigned int v0 = *(const unsigned int*)(sb + (size_t)j0 * 128);
            unsigned int v1 = *(const unsigned int*)(sb + (size_t)j1 * 128);
            unsigned int v2 = *(const unsigned int*)(sb + (size_t)j2 * 128);
            unsigned int v3 = *(const unsigned int*)(sb + (size_t)j3 * 128);
            fmax2(t0, t1, v0);
            fmax2(t0, t1, v1);
            fmax2(t0, t1, v2);
            fmax2(t0, t1, v3);
        }
    }
    t0 = fmaxf(t0, __shfl_xor(t0, 32));
    t1 = fmaxf(t1, __shfl_xor(t1, 32));
    if (h == 0) {
        unsigned int av = *(const unsigned int*)(as + (size_t)wid * 128 + c0);
        *(unsigned int*)(x1 + (size_t)wid * 64 + c0) = addrelu2(av, t0, t1);
    }
}

// ---------------- fused edge-max + epilogue, C=128 (as rows [a(128)|s(128)]) ----------------

__global__ __launch_bounds__(256) void edge_fused128_kernel(
    const unsigned short* __restrict__ as, const int* __restrict__ rowstart,
    const int* __restrict__ csr, unsigned short* __restrict__ xout) {
    int wid = (blockIdx.x * 256 + threadIdx.x) >> 6;
    int lane = threadIdx.x & 63;
    if (wid >= NN) return;
    int e0 = __builtin_amdgcn_readfirstlane(rowstart[wid]);
    int e1 = __builtin_amdgcn_readfirstlane(rowstart[wid + 1]);
    float t0 = -INFINITY, t1 = -INFINITY;
    const unsigned short* sb = as + 128 + (size_t)lane * 2;
    int nedge = e1 - e0;
    for (int base = 0; base < nedge; base += 64) {
        int rem = nedge - base;
        int myj = csr[(lane < rem) ? (e0 + base + lane) : e0];
        int cnt = rem < 64 ? rem : 64;
        int cp = (cnt + 7) & ~7;
        for (int q = 0; q < cp; q += 8) {
            int j0 = __shfl(myj, q + 0), j1 = __shfl(myj, q + 1);
            int j2 = __shfl(myj, q + 2), j3 = __shfl(myj, q + 3);
            int j4 = __shfl(myj, q + 4), j5 = __shfl(myj, q + 5);
            int j6 = __shfl(myj, q + 6), j7 = __shfl(myj, q + 7);
            unsigned int v0 = *(const unsigned int*)(sb + (size_t)j0 * 256);
            unsigned int v1 = *(const unsigned int*)(sb + (size_t)j1 * 256);
            unsigned int v2 = *(const unsigned int*)(sb + (size_t)j2 * 256);
            unsigned int v3 = *(const unsigned int*)(sb + (size_t)j3 * 256);
            unsigned int v4 = *(const unsigned int*)(sb + (size_t)j4 * 256);
            unsigned int v5 = *(const unsigned int*)(sb + (size_t)j5 * 256);
            unsigned int v6 = *(const unsigned int*)(sb + (size_t)j6 * 256);
            unsigned int v7 = *(const unsigned int*)(sb + (size_t)j7 * 256);
            fmax2(t0, t1, v0); fmax2(t0, t1, v1);
            fmax2(t0, t1, v2); fmax2(t0, t1, v3);
            fmax2(t0, t1, v4); fmax2(t0, t1, v5);
            fmax2(t0, t1, v6); fmax2(t0, t1, v7);
        }
    }
    unsigned int av = *(const unsigned int*)(as + (size_t)wid * 256 + lane * 2);
    *(unsigned int*)(xout + (size_t)wid * 128 + lane * 2) = addrelu2(av, t0, t1);
}

// ---------------- fused ef512 + h4-GEMM + W5 contraction ----------------
// Block = 16 nodes (4 waves x 4 nodes). Gather phase builds the 16x512 x3 tile in
// LDS (never written to global); MFMA phase: h = relu(X@W4t + b4) (M=16,K=512,N=256),
// epilogue contracts with W5 and atomically accumulates into out (pre-set to x+b5).
// MFMA issues from the same waves whose gather stalls dominate -> mostly hidden (m114).

__global__ __launch_bounds__(256) void ef512_w5_kernel(
    const unsigned short* __restrict__ as, const int* __restrict__ rowstart,
    const int* __restrict__ csr, const unsigned short* __restrict__ W4t,
    const float* __restrict__ b4, const float* __restrict__ W5,
    float* __restrict__ out) {
    __shared__ __align__(16) unsigned short X[16][520];  // x3 tile, +8 pad (2-way-free banks)
    int wave = threadIdx.x >> 6, lane = threadIdx.x & 63;
    int tilebase = blockIdx.x * 16;

    // ---- gather phase: this wave builds rows wave*4 .. wave*4+3 ----
    const unsigned short* sb = as + 512 + (size_t)lane * 8;
    for (int i = 0; i < 4; ++i) {
        int node = tilebase + wave * 4 + i;
        int e0 = __builtin_amdgcn_readfirstlane(rowstart[node]);
        int e1 = __builtin_amdgcn_readfirstlane(rowstart[node + 1]);
        float acc[8];
        #pragma unroll
        for (int v = 0; v < 8; ++v) acc[v] = -INFINITY;
        int nedge = e1 - e0;
        for (int base = 0; base < nedge; base += 64) {
            int rem = nedge - base;
            int myj = csr[(lane < rem) ? (e0 + base + lane) : e0];
            int cnt = rem < 64 ? rem : 64;
            int cp = (cnt + 3) & ~3;
            for (int q = 0; q < cp; q += 4) {
                int j0 = __shfl(myj, q + 0), j1 = __shfl(myj, q + 1);
                int j2 = __shfl(myj, q + 2), j3 = __shfl(myj, q + 3);
                uint4 v0 = *(const uint4*)(sb + (size_t)j0 * 1024);
                uint4 v1 = *(const uint4*)(sb + (size_t)j1 * 1024);
                uint4 v2 = *(const uint4*)(sb + (size_t)j2 * 1024);
                uint4 v3 = *(const uint4*)(sb + (size_t)j3 * 1024);
                fmax2(acc[0], acc[1], v0.x); fmax2(acc[2], acc[3], v0.y);
                fmax2(acc[4], acc[5], v0.z); fmax2(acc[6], acc[7], v0.w);
                fmax2(acc[0], acc[1], v1.x); fmax2(acc[2], acc[3], v1.y);
                fmax2(acc[4], acc[5], v1.z); fmax2(acc[6], acc[7], v1.w);
                fmax2(acc[0], acc[1], v2.x); fmax2(acc[2], acc[3], v2.y);
                fmax2(acc[4], acc[5], v2.z); fmax2(acc[6], acc[7], v2.w);
                fmax2(acc[0], acc[1], v3.x); fmax2(acc[2], acc[3], v3.y);
                fmax2(acc[4], acc[5], v3.z); fmax2(acc[6], acc[7], v3.w);
            }
        }
        uint4 av = *(const uint4*)(as + (size_t)node * 1024 + lane * 8);
        uint4 o;
        o.x = addrelu2(av.x, acc[0], acc[1]);
        o.y = addrelu2(av.y, acc[2], acc[3]);
        o.z = addrelu2(av.z, acc[4], acc[5]);
        o.w = addrelu2(av.w, acc[6], acc[7]);
        *(uint4*)&X[wave * 4 + i][lane * 8] = o;
    }
    __syncthreads();

    // ---- MFMA phase: wave handles cols [wave*64, wave*64+64) of h (N=256) ----
    int quad = lane >> 4, l16 = lane & 15;
    int colbase = wave * 64;
    f32x4 acc4[4] = {};
    for (int kc = 0; kc < 16; ++kc) {
        bf16x8 afr = *(const bf16x8*)&X[l16][kc * 32 + quad * 8];
        #pragma unroll
        for (int nt = 0; nt < 4; ++nt) {
            int col = colbase + nt * 16 + l16;
            bf16x8 bfr = *(const bf16x8*)&W4t[(size_t)col * 512 + kc * 32 + quad * 8];
            acc4[nt] = __builtin_amdgcn_mfma_f32_16x16x32_bf16(afr, bfr, acc4[nt], 0, 0, 0);
        }
    }
    // ---- epilogue: h = relu(acc + b4); out += h @ W5 ----
    float b4v[4], w5r[4][3];
    #pragma unroll
    for (int nt = 0; nt < 4; ++nt) {
        int col = colbase + nt * 16 + l16;
        b4v[nt] = b4[col];
        w5r[nt][0] = W5[col * 3 + 0];
        w5r[nt][1] = W5[col * 3 + 1];
        w5r[nt][2] = W5[col * 3 + 2];
    }
    #pragma unroll
    for (int r = 0; r < 4; ++r) {
        int row = tilebase + quad * 4 + r;
        float p0 = 0.f, p1 = 0.f, p2 = 0.f;
        #pragma unroll
        for (int nt = 0; nt < 4; ++nt) {
            float h = fmaxf(acc4[nt][r] + b4v[nt], 0.f);
            p0 += h * w5r[nt][0];
            p1 += h * w5r[nt][1];
            p2 += h * w5r[nt][2];
        }
        #pragma unroll
        for (int m = 8; m; m >>= 1) {
            p0 += __shfl_xor(p0, m);
            p1 += __shfl_xor(p1, m);
            p2 += __shfl_xor(p2, m);
        }
        if (l16 == 0) {
            atomicAdd(&out[row * 3 + 0], p0);
            atomicAdd(&out[row * 3 + 1], p1);
            atomicAdd(&out[row * 3 + 2], p2);
        }
    }
}

// ---------------- N-loop MFMA GEMM: A staged in LDS ONCE, loop over N-tiles ----------------

template<int K, int NT>
__global__ __launch_bounds__(256) void mfma_gemm_nloop_kernel(
    const unsigned short* __restrict__ A, const unsigned short* __restrict__ Bt,
    const float* __restrict__ bias, int bias_n,
    unsigned short* __restrict__ C, int M) {
    constexpr int KC = K / 32;       // k-chunks
    constexpr int N = NT * 128;
    __shared__ __align__(16) unsigned short Asl[KC][128 * 40];
    __shared__ __align__(16) unsigned short Bsl[128 * 40];
    int tid = threadIdx.x;
    int mbase = blockIdx.x * 128;
    int wave = tid >> 6, lane = tid & 63;
    int wm = (wave >> 1) * 64, wn = (wave & 1) * 64;
    int quad = lane >> 4, l16 = lane & 15;

    // stage ALL of A once: KC*512 chunks of 16B
    #pragma unroll
    for (int c = tid; c < KC * 512; c += 256) {
        int kc = c >> 9, rem = c & 511;
        int r = rem >> 2, kk = (rem & 3) * 8;
        uint4 va = make_uint4(0u, 0u, 0u, 0u);
        int gr = mbase + r;
        if (gr < M) va = *(const uint4*)&A[(size_t)gr * K + kc * 32 + kk];
        *(uint4*)&Asl[kc][r * 40 + kk] = va;
    }

    for (int nt = 0; nt < NT; ++nt) {
        int nbase = nt * 128;
        f32x4 acc[4][4] = {};
        for (int kc = 0; kc < KC; ++kc) {
            __syncthreads();
            #pragma unroll
            for (int h = 0; h < 2; ++h) {
                int c = tid + h * 256;
                int r = c >> 2, kk = (c & 3) * 8;
                uint4 vb = *(const uint4*)&Bt[(size_t)(nbase + r) * K + kc * 32 + kk];
                *(uint4*)&Bsl[r * 40 + kk] = vb;
            }
            __syncthreads();
            bf16x8 af[4], bfr[4];
            #pragma unroll
            for (int tt = 0; tt < 4; ++tt) {
                af[tt]  = *(const bf16x8*)&Asl[kc][(wm + tt * 16 + l16) * 40 + quad * 8];
                bfr[tt] = *(const bf16x8*)&Bsl[(wn + tt * 16 + l16) * 40 + quad * 8];
            }
            #pragma unroll
            for (int mt = 0; mt < 4; ++mt)
                #pragma unroll
                for (int ntt = 0; ntt < 4; ++ntt)
                    acc[mt][ntt] = __builtin_amdgcn_mfma_f32_16x16x32_bf16(
                        af[mt], bfr[ntt], acc[mt][ntt], 0, 0, 0);
        }
        #pragma unroll
        for (int mt = 0; mt < 4; ++mt) {
            #pragma unroll
            for (int r = 0; r < 4; ++r) {
                int row = mbase + wm + mt * 16 + quad * 4 + r;
                if (row >= M) continue;
                #pragma unroll
                for (int ntt = 0; ntt < 4; ++ntt) {
                    int col = nbase + wn + ntt * 16 + l16;
                    float v = acc[mt][ntt][r];
                    if (col < bias_n) v += bias[col];
                    C[(size_t)row * N + col] = f2bf(v);
                }
            }
        }
    }
}

__global__ void fallback_copy_kernel(const float* __restrict__ x, float* __restrict__ out) {
    int t = blockIdx.x * blockDim.x + threadIdx.x;
    if (t < NN * 3) out[t] = x[t];
}

// ---------------- launcher ----------------

extern "C" void kernel_launch(void* const* d_in, const int* in_sizes, int n_in,
                              void* d_out, int out_size, void* d_ws, size_t ws_size,
                              hipStream_t stream) {
    const float* x  = (const float*)d_in[0];
    const int*   ei = (const int*)d_in[1];
    const float* W1 = (const float*)d_in[2];
    const float* b1 = (const float*)d_in[3];
    const float* W2 = (const float*)d_in[4];
    const float* b2 = (const float*)d_in[5];
    const float* W3 = (const float*)d_in[6];
    const float* b3 = (const float*)d_in[7];
    const float* W4 = (const float*)d_in[8];
    const float* b4 = (const float*)d_in[9];
    const float* W5 = (const float*)d_in[10];
    const float* b5 = (const float*)d_in[11];
    float* out = (float*)d_out;

    char* p = (char*)d_ws;
    auto alloc = [&](size_t bytes) -> void* {
        void* r = (void*)p;
        p += (bytes + 255) & ~(size_t)255;
        return r;
    };
    int* deg      = (int*)alloc((size_t)NN * 4);
    int* rowstart = (int*)alloc((size_t)(NN + 1) * 4);
    int* cursor   = (int*)alloc((size_t)NN * 4);
    int* csr      = (int*)alloc((size_t)NE * 4);
    unsigned short* Bt2 = (unsigned short*)alloc(256 * 64 * 2);
    unsigned short* Bt3 = (unsigned short*)alloc(1024 * 128 * 2);
    unsigned short* W4t = (unsigned short*)alloc(256 * 512 * 2);
    unsigned short* x1 = (unsigned short*)alloc((size_t)NN * 64 * 2);
    unsigned short* x2 = (unsigned short*)alloc((size_t)NN * 128 * 2);
    unsigned short* as_slab = (unsigned short*)alloc((size_t)NN * 1024 * 2);  // as1/as2/as3
    size_t need = (size_t)(p - (char*)d_ws);
    if (ws_size < need) {
        fallback_copy_kernel<<<(NN * 3 + 255) / 256, 256, 0, stream>>>(x, out);
        return;
    }

    const int* src = ei;        // edge_index[0]
    const int* dst = ei + NE;   // edge_index[1]

    // merged setup (one dispatch)
    constexpr int SETUP_T = NN * 128 + NN * 3 + NN + NN + 8192 + 65536 + 131072;
    setup_kernel<<<(SETUP_T + 255) / 256, 256, 0, stream>>>(
        x, W1, b1, b5, W2, W3, W4, as_slab, out, deg, cursor, Bt2, Bt3, W4t);

    // CSR by dst (graph static across all 3 convs)
    hist_kernel<<<(NE + 255) / 256, 256, 0, stream>>>(dst, deg);
    scan_kernel<<<1, 1024, 0, stream>>>(deg, rowstart);
    scatter_kernel<<<(NE + 255) / 256, 256, 0, stream>>>(src, dst, rowstart, cursor, csr);

    // conv1: x1 = relu(a1 + max_j s1[j])
    edge_fused_conv1_kernel<<<12500, 256, 0, stream>>>(as_slab, rowstart, csr, x1);

    // conv2: as2 = x1 @ [Wtb2|Wb2] (+b2 on a-half); x2 = relu(a2 + max s2)
    mfma_gemm_nloop_kernel<64, 2><<<391, 256, 0, stream>>>(
        x1, Bt2, b2, 128, as_slab, NN);
    edge_fused128_kernel<<<12500, 256, 0, stream>>>(as_slab, rowstart, csr, x2);

    // conv3: as3 = x2 @ [Wtb3|Wb3] (+b3 on a-half)
    mfma_gemm_nloop_kernel<128, 8><<<391, 256, 0, stream>>>(
        x2, Bt3, b3, 512, as_slab, NN);

    // fused: x3 tile in LDS -> h = relu(X@W4+b4) -> out += h@W5  (x3 never hits HBM)
    ef512_w5_kernel<<<NN / 16, 256, 0, stream>>>(
        as_slab, rowstart, csr, W4t, b4, W5, out);
}